// Round 16
// baseline (539.173 us; speedup 1.0000x reference)
//
#include <hip/hip_runtime.h>
#include <math.h>

// GGNN encoder. B=32, N=256, D=512, E=4, N_STEPS=4.
// einsum('bnd,edh->bend') is DIAGONAL in d -> ins/outs are elementwise
// scalings. Edges 2% sparse -> sparse gather aggregation.
// Gates: wide GEMM [ain|aout|state](8192x1536) @ W_all(1536x1536), 128x128
// tile, BK=64 (16 MFMA/barrier-pair), 8 waves, 16 waves/CU, stage-early +
// counted vmcnt (r13 template, BK doubled). k_gru: 64x128, 8 waves (r15).

typedef __bf16 bf16_t;
typedef __bf16 bf16x8 __attribute__((ext_vector_type(8)));
typedef __bf16 bf16x4_t __attribute__((ext_vector_type(4)));
typedef float f32x4 __attribute__((ext_vector_type(4)));

#define SBAR() __builtin_amdgcn_s_barrier()
#define SCHED0() __builtin_amdgcn_sched_barrier(0)

// ---------------- staging: global -> LDS ----------------
// 128 rows x 32 k, 256 threads (4 waves), 2 loads/thread
__device__ __forceinline__ void stage_lds16(const bf16_t* __restrict__ g, int ld,
                                            bf16_t* __restrict__ s) {
  int wave = threadIdx.x >> 6;
  int lane = threadIdx.x & 63;
  int rsub = lane >> 2;          // 0..15
  int k0 = (lane & 3) << 3;      // 0,8,16,24
#pragma unroll
  for (int i = 0; i < 2; ++i) {
    int c = wave + (i << 2);     // chunk 0..7 (16 rows each)
    const bf16_t* gp = g + (size_t)((c << 4) + rsub) * ld + k0;
    __builtin_amdgcn_global_load_lds(
        (const __attribute__((address_space(1))) void*)gp,
        (__attribute__((address_space(3))) void*)(s + (c << 9)), 16, 0, 0);
  }
}

// 128 rows x 64 k, 512 threads, 2 loads/thread (linear idx mapping)
__device__ __forceinline__ void stage_lds16_12864(const bf16_t* __restrict__ g, int ld,
                                                  bf16_t* __restrict__ s) {
  int tid = threadIdx.x;
#pragma unroll
  for (int i = 0; i < 2; ++i) {
    int idx = tid + (i << 9);    // 0..1023
    int r = idx >> 3, k0 = (idx & 7) << 3;
    const bf16_t* gp = g + (size_t)r * ld + k0;
    __builtin_amdgcn_global_load_lds(
        (const __attribute__((address_space(1))) void*)gp,
        (__attribute__((address_space(3))) void*)(s + (idx << 3)), 16, 0, 0);
  }
}

// 64 rows x 32 k, first 256 threads of a 512-thread block, 1 load/thread
__device__ __forceinline__ void stage_lds16_64_t256(const bf16_t* __restrict__ g, int ld,
                                                    bf16_t* __restrict__ s) {
  int tid = threadIdx.x;
  if (tid < 256) {
    int r = tid >> 2;
    int k0 = (tid & 3) << 3;
    const bf16_t* gp = g + (size_t)r * ld + k0;
    __builtin_amdgcn_global_load_lds(
        (const __attribute__((address_space(1))) void*)gp,
        (__attribute__((address_space(3))) void*)(s + tid * 8), 16, 0, 0);
  }
}

// 128 rows x 32 k, 512 threads, 1 load/thread (linear tid mapping)
__device__ __forceinline__ void stage_lds16_128_lin(const bf16_t* __restrict__ g, int ld,
                                                    bf16_t* __restrict__ s) {
  int tid = threadIdx.x;
  int r = tid >> 2;
  int k0 = (tid & 3) << 3;
  const bf16_t* gp = g + (size_t)r * ld + k0;
  __builtin_amdgcn_global_load_lds(
      (const __attribute__((address_space(1))) void*)gp,
      (__attribute__((address_space(3))) void*)(s + tid * 8), 16, 0, 0);
}

__device__ __forceinline__ bf16x8 frag(const bf16_t* s, int r, int koff) {
  return *reinterpret_cast<const bf16x8*>(s + (r << 5) + koff);
}

// ---------------- prep kernels ----------------

__global__ __launch_bounds__(256) void k_build_idx(const float* __restrict__ edges,
                                                   unsigned short* __restrict__ nbr,
                                                   uchar4* __restrict__ cnt4) {
  int wid = threadIdx.x >> 6, lane = threadIdx.x & 63;
  int W = blockIdx.x * 4 + wid;          // 0..16383
  int b = W >> 9, io = (W >> 8) & 1, n = W & 255;
  const float* p = edges + (size_t)(b * 256 + n) * 2048 + io * 1024;
  unsigned short* list = nbr + (size_t)W * 64;
  int base = 0;
  int ends[4];
#pragma unroll
  for (int e = 0; e < 4; ++e) {
#pragma unroll
    for (int ch = 0; ch < 4; ++ch) {
      int c = e * 256 + ch * 64 + lane;
      float v = p[c];
      unsigned long long mask = __ballot(v != 0.0f);
      int before = __popcll(mask & ((1ull << lane) - 1ull));
      if (v != 0.0f && (base + before) < 64) list[base + before] = (unsigned short)c;
      base += __popcll(mask);
    }
    ends[e] = base < 64 ? base : 64;
  }
  if (lane == 0)
    cnt4[W] = make_uchar4((unsigned char)ends[0], (unsigned char)ends[1],
                          (unsigned char)ends[2], (unsigned char)ends[3]);
}

__global__ __launch_bounds__(256) void k_rowsum(const float* __restrict__ W,
                                                float* __restrict__ wsum, int nrows) {
  int wid = threadIdx.x >> 6, lane = threadIdx.x & 63;
  int row = blockIdx.x * 4 + wid;
  if (row >= nrows) return;
  const float4* p = reinterpret_cast<const float4*>(W + (size_t)row * 512);
  float s = 0.f;
#pragma unroll
  for (int i = 0; i < 2; ++i) {
    float4 v = p[lane + i * 64];
    s += v.x + v.y + v.z + v.w;
  }
#pragma unroll
  for (int off = 32; off > 0; off >>= 1) s += __shfl_down(s, off, 64);
  if (lane == 0) wsum[row] = s;
}

// Wall_t[n=1536][k=1536]: z=0:W_r z=1:W_z z=2:W_h(top 1024, zero-pad rest)
__global__ __launch_bounds__(256) void k_prep_wall(const float* __restrict__ Wr,
                                                   const float* __restrict__ Wz,
                                                   const float* __restrict__ Wh,
                                                   bf16_t* __restrict__ dst) {
  __shared__ float tile[32][33];
  int z = blockIdx.z;
  const float* src = z == 0 ? Wr : z == 1 ? Wz : Wh;
  int Ksrc = z == 2 ? 1024 : 1536;
  bf16_t* d = dst + (size_t)(z * 512) * 1536;
  int tx = threadIdx.x & 31, ty = threadIdx.x >> 5;
  int n0 = blockIdx.x * 32, k0 = blockIdx.y * 32;
  if (k0 >= Ksrc) {
#pragma unroll
    for (int i = 0; i < 4; ++i)
      d[(size_t)(n0 + ty + i * 8) * 1536 + k0 + tx] = (bf16_t)0.0f;
    return;
  }
#pragma unroll
  for (int i = 0; i < 4; ++i)
    tile[ty + i * 8][tx] = src[(size_t)(k0 + ty + i * 8) * 512 + n0 + tx];
  __syncthreads();
#pragma unroll
  for (int i = 0; i < 4; ++i)
    d[(size_t)(n0 + ty + i * 8) * 1536 + k0 + tx] = (bf16_t)tile[tx][ty + i * 8];
}

// three 512x512 transposes: z=0: Whb (from W_h rows 1024:1536), z=1: Wbh, z=2: Wbc
__global__ __launch_bounds__(256) void k_prep_small(const float* __restrict__ Whb_src,
                                                    const float* __restrict__ Wbh_src,
                                                    const float* __restrict__ Wbc_src,
                                                    bf16_t* __restrict__ Whb_t,
                                                    bf16_t* __restrict__ Wbh_t,
                                                    bf16_t* __restrict__ Wbc_t) {
  __shared__ float tile[32][33];
  int z = blockIdx.z;
  const float* src = z == 0 ? Whb_src : z == 1 ? Wbh_src : Wbc_src;
  bf16_t* dst = z == 0 ? Whb_t : z == 1 ? Wbh_t : Wbc_t;
  int tx = threadIdx.x & 31, ty = threadIdx.x >> 5;
  int n0 = blockIdx.x * 32, k0 = blockIdx.y * 32;
#pragma unroll
  for (int i = 0; i < 4; ++i)
    tile[ty + i * 8][tx] = src[(size_t)(k0 + ty + i * 8) * 512 + n0 + tx];
  __syncthreads();
#pragma unroll
  for (int i = 0; i < 4; ++i)
    dst[(size_t)(n0 + ty + i * 8) * 512 + k0 + tx] = (bf16_t)tile[tx][ty + i * 8];
}

__global__ __launch_bounds__(256) void k_state_init(const float* __restrict__ src,
                                                    float* __restrict__ dst_f32,
                                                    bf16_t* __restrict__ dst_b, int n4) {
  int i = blockIdx.x * 256 + threadIdx.x;
  if (i < n4) {
    float4 v = reinterpret_cast<const float4*>(src)[i];
    reinterpret_cast<float4*>(dst_f32)[i] = v;
    bf16x4_t o;
    o[0] = (bf16_t)v.x; o[1] = (bf16_t)v.y; o[2] = (bf16_t)v.z; o[3] = (bf16_t)v.w;
    *reinterpret_cast<bf16x4_t*>(dst_b + i * 4) = o;
  }
}

// ---------------- sparse aggregation ----------------
__global__ __launch_bounds__(256) void k_agg_sparse(const unsigned short* __restrict__ nbr,
                                                    const uchar4* __restrict__ cnt4,
                                                    const bf16_t* __restrict__ state_b,
                                                    const float* __restrict__ wsum_in,
                                                    const float* __restrict__ wsum_out,
                                                    const float* __restrict__ b_in,
                                                    const float* __restrict__ b_out,
                                                    bf16_t* __restrict__ ain_b,
                                                    bf16_t* __restrict__ aout_b) {
  int wid = threadIdx.x >> 6, lane = threadIdx.x & 63;
  int W = blockIdx.x * 4 + wid;          // 0..16383
  int b = W >> 9, io = (W >> 8) & 1, n = W & 255;
  const float* wsel = io ? wsum_out : wsum_in;
  const float* bsel = io ? b_out : b_in;
  int d0 = lane << 3;
  float w[4][8], bi[4][8];
#pragma unroll
  for (int e = 0; e < 4; ++e) {
#pragma unroll
    for (int t = 0; t < 8; t += 4) {
      float4 v = *reinterpret_cast<const float4*>(wsel + e * 512 + d0 + t);
      w[e][t] = v.x; w[e][t + 1] = v.y; w[e][t + 2] = v.z; w[e][t + 3] = v.w;
      float4 u = *reinterpret_cast<const float4*>(bsel + e * 512 + d0 + t);
      bi[e][t] = u.x; bi[e][t + 1] = u.y; bi[e][t + 2] = u.z; bi[e][t + 3] = u.w;
    }
  }
  int mycode = nbr[(size_t)W * 64 + lane];
  uchar4 ce = cnt4[W];
  float acc[8];
#pragma unroll
  for (int t = 0; t < 8; ++t) acc[t] = 0.f;
  const bf16_t* Sb = state_b + ((size_t)b << 17) + d0;
  int start = 0;
#pragma unroll
  for (int e = 0; e < 4; ++e) {
    int end = (e == 0) ? ce.x : (e == 1) ? ce.y : (e == 2) ? ce.z : ce.w;
    float fc = (float)(end - start);
#pragma unroll
    for (int t = 0; t < 8; ++t) acc[t] += fc * bi[e][t];
    for (int j = start; j < end; ++j) {
      int c = __shfl(mycode, j, 64);
      int m = c & 255;
      bf16x8 s = *reinterpret_cast<const bf16x8*>(Sb + ((size_t)m << 9));
#pragma unroll
      for (int t = 0; t < 8; ++t) acc[t] += (float)s[t] * w[e][t];
    }
    start = end;
  }
  bf16x8 o;
#pragma unroll
  for (int t = 0; t < 8; ++t) o[t] = (bf16_t)acc[t];
  bf16_t* dst = io ? aout_b : ain_b;
  *reinterpret_cast<bf16x8*>(dst + (size_t)(b * 256 + n) * 512 + d0) = o;
}

// ---------------- wide gate GEMM: 128x128, BK=64, 8 waves ------------------
// grid (64, 12); nt 0-3: r -> rs_b ; 4-7: z -> zb_b ; 8-11: h (K=1024) -> hp_b.
// Wave tile 64x32: wr = wid>>2, wc = wid&3. 2 blocks/CU = 16 waves/CU.
// Per K-tile: 16 MFMA per wave between barrier pairs (2 ks sub-blocks).
__global__ __launch_bounds__(512, 4) void k_gates(const bf16_t* __restrict__ ain_b,
                                                  const bf16_t* __restrict__ aout_b,
                                                  const bf16_t* __restrict__ state_row_b,
                                                  const bf16_t* __restrict__ Wall_t,
                                                  const float* __restrict__ b_r,
                                                  const float* __restrict__ b_z,
                                                  const float* __restrict__ b_h,
                                                  bf16_t* __restrict__ rs_b,
                                                  bf16_t* __restrict__ zb_b,
                                                  bf16_t* __restrict__ hp_b) {
  __shared__ __align__(16) char smem[65536];   // 2 bufs x (A 16KB + B 16KB)
  float* tr = (float*)smem;                    // epilogue reuse [128][36] = 18KB
  int tid = threadIdx.x;
  int lane = tid & 63, wid = tid >> 6;         // 8 waves
  int wr = wid >> 2, wc = wid & 3;             // 2M x 4N
  int mt = blockIdx.x, nt = blockIdx.y;        // 64 x 12
  int gm0 = mt * 128, gn0 = nt * 128;
  int l15 = lane & 15, q = lane >> 4;
  int nkt = (nt < 8) ? 24 : 16;                // K-tiles of 64
  f32x4 acc[4][2];
#pragma unroll
  for (int i = 0; i < 4; ++i)
#pragma unroll
    for (int j = 0; j < 2; ++j) acc[i][j] = f32x4{0.f, 0.f, 0.f, 0.f};

  auto stageAB = [&](int buf, int kt) {        // 4 loads/thread (2 A + 2 B)
    int blk = kt >> 3, kk = (kt & 7) << 6;
    const bf16_t* gA = (blk == 0 ? ain_b : blk == 1 ? aout_b : state_row_b)
                       + (size_t)gm0 * 512 + kk;
    bf16_t* base = (bf16_t*)(smem + buf * 32768);
    stage_lds16_12864(gA, 512, base);                                    // A 16KB
    stage_lds16_12864(Wall_t + (size_t)gn0 * 1536 + (kt << 6), 1536,
                      base + 8192);                                      // B 16KB
  };

  stageAB(0, 0);
  stageAB(1, 1);                               // 8 loads in flight per thread
  for (int kt = 0; kt < nkt; ++kt) {
    if (kt + 1 < nkt)
      asm volatile("s_waitcnt vmcnt(4)" ::: "memory");   // tile kt's loads done
    else
      asm volatile("s_waitcnt vmcnt(0)" ::: "memory");
    SCHED0(); SBAR(); SCHED0();                // publish tile kt to all waves
    const bf16_t* As = (const bf16_t*)(smem + (kt & 1) * 32768);
    const bf16_t* Bs = As + 8192;
#pragma unroll
    for (int ks = 0; ks < 2; ++ks) {
      int koff2 = (ks << 5) + (q << 3);
      bf16x8 af[4], bfr[2];
#pragma unroll
      for (int i = 0; i < 4; ++i)
        af[i] = *reinterpret_cast<const bf16x8*>(As + ((wr * 64 + i * 16 + l15) << 6) + koff2);
#pragma unroll
      for (int j = 0; j < 2; ++j)
        bfr[j] = *reinterpret_cast<const bf16x8*>(Bs + ((wc * 32 + j * 16 + l15) << 6) + koff2);
#pragma unroll
      for (int i = 0; i < 4; ++i)
#pragma unroll
        for (int j = 0; j < 2; ++j)
          acc[i][j] = __builtin_amdgcn_mfma_f32_16x16x32_bf16(af[i], bfr[j], acc[i][j], 0, 0, 0);
    }
    SCHED0(); SBAR(); SCHED0();                // all waves done reading this buf
    if (kt + 2 < nkt) stageAB(kt & 1, kt + 2); // refill; waited at iter kt+2
  }

  // coalesced epilogue: 4 passes of 128x32 via padded LDS transpose (r13)
  int region = nt >> 2;                        // 0:r 1:z 2:h
  int cn0 = gn0 - region * 512;                // local col base in [0,512)
  const float* bias = region == 0 ? b_r : region == 1 ? b_z : b_h;
#pragma unroll
  for (int p = 0; p < 4; ++p) {
    __syncthreads();
    if (wc == p) {                             // 2 waves (wr=0,1) cover 128 rows
#pragma unroll
      for (int i = 0; i < 4; ++i)
#pragma unroll
        for (int j = 0; j < 2; ++j)
#pragma unroll
          for (int rr = 0; rr < 4; ++rr)
            tr[(wr * 64 + i * 16 + q * 4 + rr) * 36 + j * 16 + l15] = acc[i][j][rr];
    }
    __syncthreads();
#pragma unroll
    for (int s = 0; s < 8; ++s) {
      int e = tid + (s << 9);                  // 0..4095
      int row = e >> 5, c = e & 31;
      int col = cn0 + (p << 5) + c;
      size_t idx = (size_t)(gm0 + row) * 512 + col;
      float x = tr[row * 36 + c] + bias[col];
      if (region == 0) {
        float rg = 1.0f / (1.0f + __expf(-x));
        rs_b[idx] = (bf16_t)(rg * (float)state_row_b[idx]);
      } else if (region == 1) {
        zb_b[idx] = (bf16_t)(1.0f / (1.0f + __expf(-x)));
      } else {
        hp_b[idx] = (bf16_t)x;
      }
    }
  }
}

// ---------------- small GEMM + GRU update: 64x128, 8 waves (r15) -----------
__global__ __launch_bounds__(512, 4) void k_gru(const bf16_t* __restrict__ rs_b,
                                                const bf16_t* __restrict__ Whb_t,
                                                const bf16_t* __restrict__ hp_b,
                                                const bf16_t* __restrict__ zb_b,
                                                float* __restrict__ state_f32,
                                                bf16_t* __restrict__ state_row_b) {
  __shared__ __align__(16) char smem[24576];   // 2 bufs x (A 4KB + B 8KB)
  float* tr = (float*)smem;                    // epilogue reuse [64][36]
  int tid = threadIdx.x;
  int lane = tid & 63, wid = tid >> 6;         // 8 waves
  int wr = wid >> 2, wc = wid & 3;             // 2M x 4N
  int mt = blockIdx.x, nt = blockIdx.y;        // 128 x 4
  int gm0 = mt * 64, gn0 = nt * 128;
  int l15 = lane & 15, q = lane >> 4, koff = q << 3;
  f32x4 acc[2][2];
#pragma unroll
  for (int i = 0; i < 2; ++i)
#pragma unroll
    for (int j = 0; j < 2; ++j) acc[i][j] = f32x4{0.f, 0.f, 0.f, 0.f};

  auto stageAB = [&](int buf, int kt) {
    bf16_t* base = (bf16_t*)(smem + buf * 12288);
    stage_lds16_64_t256(rs_b + (size_t)gm0 * 512 + (kt << 5), 512, base);  // A 4KB
    stage_lds16_128_lin(Whb_t + (size_t)gn0 * 512 + (kt << 5), 512,
                        base + 2048);                                      // B 8KB
  };

  stageAB(0, 0);
  __syncthreads();                             // compiler-managed drain + barrier
  int cur = 0;
  for (int kt = 0; kt < 16; ++kt) {
    if (kt + 1 < 16) stageAB(cur ^ 1, kt + 1); // issue BEFORE compute
    const bf16_t* As = (const bf16_t*)(smem + cur * 12288);
    const bf16_t* Bs = As + 2048;
    bf16x8 af[2], bfr[2];
#pragma unroll
    for (int i = 0; i < 2; ++i) af[i] = frag(As, wr * 32 + i * 16 + l15, koff);
#pragma unroll
    for (int j = 0; j < 2; ++j) bfr[j] = frag(Bs, wc * 32 + j * 16 + l15, koff);
#pragma unroll
    for (int i = 0; i < 2; ++i)
#pragma unroll
      for (int j = 0; j < 2; ++j)
        acc[i][j] = __builtin_amdgcn_mfma_f32_16x16x32_bf16(af[i], bfr[j], acc[i][j], 0, 0, 0);
    __syncthreads();                           // next tile staged + this read-done
    cur ^= 1;
  }

  // coalesced epilogue: 4 passes of 64x32 via padded LDS transpose
#pragma unroll
  for (int p = 0; p < 4; ++p) {
    __syncthreads();
    if (wc == p) {                             // 2 waves (wr=0,1) cover 64 rows
#pragma unroll
      for (int i = 0; i < 2; ++i)
#pragma unroll
        for (int j = 0; j < 2; ++j)
#pragma unroll
          for (int rr = 0; rr < 4; ++rr)
            tr[(wr * 32 + i * 16 + q * 4 + rr) * 36 + j * 16 + l15] = acc[i][j][rr];
    }
    __syncthreads();
#pragma unroll
    for (int s = 0; s < 4; ++s) {
      int e = tid + (s << 9);                  // 0..2047
      int row = e >> 5, c = e & 31;
      int col = gn0 + (p << 5) + c;
      size_t idx = (size_t)(gm0 + row) * 512 + col;
      float x = tr[row * 36 + c] + (float)hp_b[idx];
      float hh = x > 0.0f ? x : 0.01f * x;
      float z = (float)zb_b[idx];
      float so = state_f32[idx];
      float sn = (1.0f - z) * so + z * hh;
      state_f32[idx] = sn;
      state_row_b[idx] = (bf16_t)sn;
    }
  }
}

// ---------------- bridge ----------------

__global__ __launch_bounds__(256) void k_join(const float* __restrict__ state_f32,
                                              bf16_t* __restrict__ join_b) {
  int idx = blockIdx.x * 256 + threadIdx.x;
  float s = 0.f;
#pragma unroll
  for (int b = 0; b < 32; ++b) s += state_f32[(size_t)b * 131072 + idx];
  join_b[idx] = (bf16_t)(s * (1.0f / 32.0f));
}

__global__ __launch_bounds__(256) void k_bridge(const bf16_t* __restrict__ join_b,
                                                const bf16_t* __restrict__ Wbh_t,
                                                const bf16_t* __restrict__ Wbc_t,
                                                const float* __restrict__ b_bh,
                                                const float* __restrict__ b_bc,
                                                float* __restrict__ out_h,
                                                float* __restrict__ out_c) {
  __shared__ bf16_t As[2][4096];
  __shared__ bf16_t Bs[2][4096];
  int mt = blockIdx.x, nt = blockIdx.y, hc = blockIdx.z;
  const bf16_t* Wt = hc ? Wbc_t : Wbh_t;
  const float* bias = hc ? b_bc : b_bh;
  float* dst = hc ? out_c : out_h;
  int gm0 = mt * 128, gn0 = nt * 128;
  int lane = threadIdx.x & 63, wid = threadIdx.x >> 6;
  int wr = wid >> 1, wc = wid & 1;
  int l15 = lane & 15, koff = (lane >> 4) << 3;
  f32x4 acc[4][4];
#pragma unroll
  for (int i = 0; i < 4; ++i)
#pragma unroll
    for (int j = 0; j < 4; ++j) acc[i][j] = f32x4{0.f, 0.f, 0.f, 0.f};
  auto stageAB = [&](int buf, int kt) {
    stage_lds16(join_b + (size_t)gm0 * 512 + (kt << 5), 512, As[buf]);
    stage_lds16(Wt + (size_t)gn0 * 512 + (kt << 5), 512, Bs[buf]);
  };
  stageAB(0, 0);
  __syncthreads();
  int cur = 0;
  for (int kt = 0; kt < 16; ++kt) {
    if (kt + 1 < 16) stageAB(cur ^ 1, kt + 1);
    bf16x8 af[4], bfr[4];
#pragma unroll
    for (int i = 0; i < 4; ++i) af[i] = frag(As[cur], wr * 64 + i * 16 + l15, koff);
#pragma unroll
    for (int j = 0; j < 4; ++j) bfr[j] = frag(Bs[cur], wc * 64 + j * 16 + l15, koff);
#pragma unroll
    for (int i = 0; i < 4; ++i)
#pragma unroll
      for (int j = 0; j < 4; ++j)
        acc[i][j] = __builtin_amdgcn_mfma_f32_16x16x32_bf16(af[i], bfr[j], acc[i][j], 0, 0, 0);
    __syncthreads();
    cur ^= 1;
  }
  int lr0 = (lane >> 4) << 2;
#pragma unroll
  for (int j = 0; j < 4; ++j) {
    int col = gn0 + wc * 64 + j * 16 + l15;
    float bv = bias[col];
#pragma unroll
    for (int i = 0; i < 4; ++i) {
#pragma unroll
      for (int r = 0; r < 4; ++r) {
        int row = gm0 + wr * 64 + i * 16 + lr0 + r;
        float v = acc[i][j][r] + bv;
        v = v > 0.f ? v : 0.f;
#pragma unroll
        for (int rep = 0; rep < 4; ++rep)
          dst[(size_t)rep * 131072 + (size_t)row * 512 + col] = v;
      }
    }
  }
}

// ---------------- launch ----------------

extern "C" void kernel_launch(void* const* d_in, const int* in_sizes, int n_in,
                              void* d_out, int out_size, void* d_ws, size_t ws_size,
                              hipStream_t stream) {
  const float* prop_state = (const float*)d_in[0];
  const float* edges = (const float*)d_in[1];
  const float* W_in = (const float*)d_in[2];
  const float* b_in = (const float*)d_in[3];
  const float* W_out = (const float*)d_in[4];
  const float* b_out = (const float*)d_in[5];
  const float* W_r = (const float*)d_in[6];
  const float* b_r = (const float*)d_in[7];
  const float* W_z = (const float*)d_in[8];
  const float* b_z = (const float*)d_in[9];
  const float* W_h = (const float*)d_in[10];
  const float* b_h = (const float*)d_in[11];
  const float* W_bh = (const float*)d_in[12];
  const float* b_bh = (const float*)d_in[13];
  const float* W_bc = (const float*)d_in[14];
  const float* b_bc = (const float*)d_in[15];

  float* out_state = (float*)d_out;          // 32*256*512 f32
  float* out_h = out_state + 4194304;        // 4*256*512
  float* out_c = out_h + 524288;

  char* ws = (char*)d_ws;
  size_t off = 0;
  auto alloc = [&](size_t bytes) -> void* {
    void* p = ws + off;
    off += (bytes + 255) & ~(size_t)255;
    return p;
  };
  unsigned short* nbr = (unsigned short*)alloc(16384ull * 64 * 2);
  uchar4* cnt4   = (uchar4*)alloc(16384ull * 4);
  float* wsum_in  = (float*)alloc(2048ull * 4);
  float* wsum_out = (float*)alloc(2048ull * 4);
  bf16_t* Wall_t = (bf16_t*)alloc(1536ull * 1536 * 2); // [n=1536][k=1536]
  bf16_t* Whb_t  = (bf16_t*)alloc(512ull * 512 * 2);   // W_h rows 1024:1536
  bf16_t* Wbh_t  = (bf16_t*)alloc(512ull * 512 * 2);
  bf16_t* Wbc_t  = (bf16_t*)alloc(512ull * 512 * 2);
  bf16_t* state_b = (bf16_t*)alloc(4194304ull * 2);    // row-major bf16 state
  bf16_t* ain_b  = (bf16_t*)alloc(4194304ull * 2);
  bf16_t* aout_b = (bf16_t*)alloc(4194304ull * 2);
  bf16_t* rs_b   = (bf16_t*)alloc(4194304ull * 2);
  bf16_t* zb_b   = (bf16_t*)alloc(4194304ull * 2);
  bf16_t* hp_b   = (bf16_t*)alloc(4194304ull * 2);
  bf16_t* join_b = (bf16_t*)alloc(131072ull * 2);
  if (off > ws_size) return;  // insufficient workspace -> output stays poisoned

  // prep
  k_build_idx<<<4096, 256, 0, stream>>>(edges, nbr, cnt4);
  k_rowsum<<<512, 256, 0, stream>>>(W_in, wsum_in, 2048);
  k_rowsum<<<512, 256, 0, stream>>>(W_out, wsum_out, 2048);
  k_prep_wall<<<dim3(16, 48, 3), 256, 0, stream>>>(W_r, W_z, W_h, Wall_t);
  k_prep_small<<<dim3(16, 16, 3), 256, 0, stream>>>(W_h + 1024 * 512, W_bh, W_bc,
                                                    Whb_t, Wbh_t, Wbc_t);
  k_state_init<<<4096, 256, 0, stream>>>(prop_state, out_state, state_b, 1048576);

  // 4 propagation steps
  for (int step = 0; step < 4; ++step) {
    k_agg_sparse<<<4096, 256, 0, stream>>>(nbr, cnt4, state_b, wsum_in, wsum_out,
                                           b_in, b_out, ain_b, aout_b);
    k_gates<<<dim3(64, 12), 512, 0, stream>>>(ain_b, aout_b, state_b, Wall_t,
                                              b_r, b_z, b_h, rs_b, zb_b, hp_b);
    k_gru<<<dim3(128, 4), 512, 0, stream>>>(rs_b, Whb_t, hp_b, zb_b,
                                            out_state, state_b);
  }

  // bridge
  k_join<<<512, 256, 0, stream>>>(out_state, join_b);
  k_bridge<<<dim3(2, 4, 2), 256, 0, stream>>>(join_b, Wbh_t, Wbc_t, b_bh, b_bc, out_h, out_c);
}

// Round 17
// 491.568 us; speedup vs baseline: 1.0968x; 1.0968x over previous
//
#include <hip/hip_runtime.h>
#include <math.h>

// GGNN encoder. B=32, N=256, D=512, E=4, N_STEPS=4.  [ROUND-13 BEST CONFIG]
// einsum('bnd,edh->bend') is DIAGONAL in d -> ins/outs are elementwise
// scalings. Edges 2% sparse -> sparse gather aggregation.
// Gates: wide GEMM [ain|aout|state](8192x1536) @ W_all(1536x1536), 128x128
// tile, 8 waves (wave tile 64x32), BK=32, 24 waves/CU (measured optimum:
// 58us, 593 TF). k_gru: 64x128, 4 waves. Coalesced LDS-transpose epilogues.

typedef __bf16 bf16_t;
typedef __bf16 bf16x8 __attribute__((ext_vector_type(8)));
typedef __bf16 bf16x4_t __attribute__((ext_vector_type(4)));
typedef float f32x4 __attribute__((ext_vector_type(4)));

#define SBAR() __builtin_amdgcn_s_barrier()
#define SCHED0() __builtin_amdgcn_sched_barrier(0)

// ---------------- staging: global -> LDS ----------------
// 128 rows x 32 k, 256 threads (4 waves), 2 loads/thread
__device__ __forceinline__ void stage_lds16(const bf16_t* __restrict__ g, int ld,
                                            bf16_t* __restrict__ s) {
  int wave = threadIdx.x >> 6;
  int lane = threadIdx.x & 63;
  int rsub = lane >> 2;          // 0..15
  int k0 = (lane & 3) << 3;      // 0,8,16,24
#pragma unroll
  for (int i = 0; i < 2; ++i) {
    int c = wave + (i << 2);     // chunk 0..7 (16 rows each)
    const bf16_t* gp = g + (size_t)((c << 4) + rsub) * ld + k0;
    __builtin_amdgcn_global_load_lds(
        (const __attribute__((address_space(1))) void*)gp,
        (__attribute__((address_space(3))) void*)(s + (c << 9)), 16, 0, 0);
  }
}

// 64 rows x 32 k, 256 threads, 1 load/thread
__device__ __forceinline__ void stage_lds16_64(const bf16_t* __restrict__ g, int ld,
                                               bf16_t* __restrict__ s) {
  int wave = threadIdx.x >> 6;
  int lane = threadIdx.x & 63;
  int rsub = lane >> 2;
  int k0 = (lane & 3) << 3;
  const bf16_t* gp = g + (size_t)((wave << 4) + rsub) * ld + k0;
  __builtin_amdgcn_global_load_lds(
      (const __attribute__((address_space(1))) void*)gp,
      (__attribute__((address_space(3))) void*)(s + (wave << 9)), 16, 0, 0);
}

// 128 rows x 32 k, 512 threads (8 waves), 1 load/thread
__device__ __forceinline__ void stage_lds16_128_w8(const bf16_t* __restrict__ g, int ld,
                                                   bf16_t* __restrict__ s) {
  int wave = threadIdx.x >> 6;   // 0..7
  int lane = threadIdx.x & 63;
  int rsub = lane >> 2;
  int k0 = (lane & 3) << 3;
  const bf16_t* gp = g + (size_t)((wave << 4) + rsub) * ld + k0;
  __builtin_amdgcn_global_load_lds(
      (const __attribute__((address_space(1))) void*)gp,
      (__attribute__((address_space(3))) void*)(s + (wave << 9)), 16, 0, 0);
}

__device__ __forceinline__ bf16x8 frag(const bf16_t* s, int r, int koff) {
  return *reinterpret_cast<const bf16x8*>(s + (r << 5) + koff);
}

// ---------------- prep kernels ----------------

__global__ __launch_bounds__(256) void k_build_idx(const float* __restrict__ edges,
                                                   unsigned short* __restrict__ nbr,
                                                   uchar4* __restrict__ cnt4) {
  int wid = threadIdx.x >> 6, lane = threadIdx.x & 63;
  int W = blockIdx.x * 4 + wid;          // 0..16383
  int b = W >> 9, io = (W >> 8) & 1, n = W & 255;
  const float* p = edges + (size_t)(b * 256 + n) * 2048 + io * 1024;
  unsigned short* list = nbr + (size_t)W * 64;
  int base = 0;
  int ends[4];
#pragma unroll
  for (int e = 0; e < 4; ++e) {
#pragma unroll
    for (int ch = 0; ch < 4; ++ch) {
      int c = e * 256 + ch * 64 + lane;
      float v = p[c];
      unsigned long long mask = __ballot(v != 0.0f);
      int before = __popcll(mask & ((1ull << lane) - 1ull));
      if (v != 0.0f && (base + before) < 64) list[base + before] = (unsigned short)c;
      base += __popcll(mask);
    }
    ends[e] = base < 64 ? base : 64;
  }
  if (lane == 0)
    cnt4[W] = make_uchar4((unsigned char)ends[0], (unsigned char)ends[1],
                          (unsigned char)ends[2], (unsigned char)ends[3]);
}

__global__ __launch_bounds__(256) void k_rowsum(const float* __restrict__ W,
                                                float* __restrict__ wsum, int nrows) {
  int wid = threadIdx.x >> 6, lane = threadIdx.x & 63;
  int row = blockIdx.x * 4 + wid;
  if (row >= nrows) return;
  const float4* p = reinterpret_cast<const float4*>(W + (size_t)row * 512);
  float s = 0.f;
#pragma unroll
  for (int i = 0; i < 2; ++i) {
    float4 v = p[lane + i * 64];
    s += v.x + v.y + v.z + v.w;
  }
#pragma unroll
  for (int off = 32; off > 0; off >>= 1) s += __shfl_down(s, off, 64);
  if (lane == 0) wsum[row] = s;
}

// Wall_t[n=1536][k=1536]: z=0:W_r z=1:W_z z=2:W_h(top 1024, zero-pad rest)
__global__ __launch_bounds__(256) void k_prep_wall(const float* __restrict__ Wr,
                                                   const float* __restrict__ Wz,
                                                   const float* __restrict__ Wh,
                                                   bf16_t* __restrict__ dst) {
  __shared__ float tile[32][33];
  int z = blockIdx.z;
  const float* src = z == 0 ? Wr : z == 1 ? Wz : Wh;
  int Ksrc = z == 2 ? 1024 : 1536;
  bf16_t* d = dst + (size_t)(z * 512) * 1536;
  int tx = threadIdx.x & 31, ty = threadIdx.x >> 5;
  int n0 = blockIdx.x * 32, k0 = blockIdx.y * 32;
  if (k0 >= Ksrc) {
#pragma unroll
    for (int i = 0; i < 4; ++i)
      d[(size_t)(n0 + ty + i * 8) * 1536 + k0 + tx] = (bf16_t)0.0f;
    return;
  }
#pragma unroll
  for (int i = 0; i < 4; ++i)
    tile[ty + i * 8][tx] = src[(size_t)(k0 + ty + i * 8) * 512 + n0 + tx];
  __syncthreads();
#pragma unroll
  for (int i = 0; i < 4; ++i)
    d[(size_t)(n0 + ty + i * 8) * 1536 + k0 + tx] = (bf16_t)tile[tx][ty + i * 8];
}

// three 512x512 transposes: z=0: Whb (from W_h rows 1024:1536), z=1: Wbh, z=2: Wbc
__global__ __launch_bounds__(256) void k_prep_small(const float* __restrict__ Whb_src,
                                                    const float* __restrict__ Wbh_src,
                                                    const float* __restrict__ Wbc_src,
                                                    bf16_t* __restrict__ Whb_t,
                                                    bf16_t* __restrict__ Wbh_t,
                                                    bf16_t* __restrict__ Wbc_t) {
  __shared__ float tile[32][33];
  int z = blockIdx.z;
  const float* src = z == 0 ? Whb_src : z == 1 ? Wbh_src : Wbc_src;
  bf16_t* dst = z == 0 ? Whb_t : z == 1 ? Wbh_t : Wbc_t;
  int tx = threadIdx.x & 31, ty = threadIdx.x >> 5;
  int n0 = blockIdx.x * 32, k0 = blockIdx.y * 32;
#pragma unroll
  for (int i = 0; i < 4; ++i)
    tile[ty + i * 8][tx] = src[(size_t)(k0 + ty + i * 8) * 512 + n0 + tx];
  __syncthreads();
#pragma unroll
  for (int i = 0; i < 4; ++i)
    dst[(size_t)(n0 + ty + i * 8) * 512 + k0 + tx] = (bf16_t)tile[tx][ty + i * 8];
}

__global__ __launch_bounds__(256) void k_state_init(const float* __restrict__ src,
                                                    float* __restrict__ dst_f32,
                                                    bf16_t* __restrict__ dst_b, int n4) {
  int i = blockIdx.x * 256 + threadIdx.x;
  if (i < n4) {
    float4 v = reinterpret_cast<const float4*>(src)[i];
    reinterpret_cast<float4*>(dst_f32)[i] = v;
    bf16x4_t o;
    o[0] = (bf16_t)v.x; o[1] = (bf16_t)v.y; o[2] = (bf16_t)v.z; o[3] = (bf16_t)v.w;
    *reinterpret_cast<bf16x4_t*>(dst_b + i * 4) = o;
  }
}

// ---------------- sparse aggregation ----------------
__global__ __launch_bounds__(256) void k_agg_sparse(const unsigned short* __restrict__ nbr,
                                                    const uchar4* __restrict__ cnt4,
                                                    const bf16_t* __restrict__ state_b,
                                                    const float* __restrict__ wsum_in,
                                                    const float* __restrict__ wsum_out,
                                                    const float* __restrict__ b_in,
                                                    const float* __restrict__ b_out,
                                                    bf16_t* __restrict__ ain_b,
                                                    bf16_t* __restrict__ aout_b) {
  int wid = threadIdx.x >> 6, lane = threadIdx.x & 63;
  int W = blockIdx.x * 4 + wid;          // 0..16383
  int b = W >> 9, io = (W >> 8) & 1, n = W & 255;
  const float* wsel = io ? wsum_out : wsum_in;
  const float* bsel = io ? b_out : b_in;
  int d0 = lane << 3;
  float w[4][8], bi[4][8];
#pragma unroll
  for (int e = 0; e < 4; ++e) {
#pragma unroll
    for (int t = 0; t < 8; t += 4) {
      float4 v = *reinterpret_cast<const float4*>(wsel + e * 512 + d0 + t);
      w[e][t] = v.x; w[e][t + 1] = v.y; w[e][t + 2] = v.z; w[e][t + 3] = v.w;
      float4 u = *reinterpret_cast<const float4*>(bsel + e * 512 + d0 + t);
      bi[e][t] = u.x; bi[e][t + 1] = u.y; bi[e][t + 2] = u.z; bi[e][t + 3] = u.w;
    }
  }
  int mycode = nbr[(size_t)W * 64 + lane];
  uchar4 ce = cnt4[W];
  float acc[8];
#pragma unroll
  for (int t = 0; t < 8; ++t) acc[t] = 0.f;
  const bf16_t* Sb = state_b + ((size_t)b << 17) + d0;
  int start = 0;
#pragma unroll
  for (int e = 0; e < 4; ++e) {
    int end = (e == 0) ? ce.x : (e == 1) ? ce.y : (e == 2) ? ce.z : ce.w;
    float fc = (float)(end - start);
#pragma unroll
    for (int t = 0; t < 8; ++t) acc[t] += fc * bi[e][t];
    for (int j = start; j < end; ++j) {
      int c = __shfl(mycode, j, 64);
      int m = c & 255;
      bf16x8 s = *reinterpret_cast<const bf16x8*>(Sb + ((size_t)m << 9));
#pragma unroll
      for (int t = 0; t < 8; ++t) acc[t] += (float)s[t] * w[e][t];
    }
    start = end;
  }
  bf16x8 o;
#pragma unroll
  for (int t = 0; t < 8; ++t) o[t] = (bf16_t)acc[t];
  bf16_t* dst = io ? aout_b : ain_b;
  *reinterpret_cast<bf16x8*>(dst + (size_t)(b * 256 + n) * 512 + d0) = o;
}

// ---------------- wide gate GEMM: 128x128, 8 waves, BK=32 (r13 optimum) ----
// grid (64, 12); nt 0-3: r -> rs_b ; 4-7: z -> zb_b ; 8-11: h (K=1024) -> hp_b.
// Wave tile 64x32: wr = wid>>2, wc = wid&3. 24 waves/CU.
__global__ __launch_bounds__(512, 6) void k_gates(const bf16_t* __restrict__ ain_b,
                                                  const bf16_t* __restrict__ aout_b,
                                                  const bf16_t* __restrict__ state_row_b,
                                                  const bf16_t* __restrict__ Wall_t,
                                                  const float* __restrict__ b_r,
                                                  const float* __restrict__ b_z,
                                                  const float* __restrict__ b_h,
                                                  bf16_t* __restrict__ rs_b,
                                                  bf16_t* __restrict__ zb_b,
                                                  bf16_t* __restrict__ hp_b) {
  __shared__ __align__(16) char smem[32768];   // 2 bufs x (A 8KB + B 8KB)
  float* tr = (float*)smem;                    // epilogue reuse [128][36] = 18KB
  int tid = threadIdx.x;
  int lane = tid & 63, wid = tid >> 6;         // 8 waves
  int wr = wid >> 2, wc = wid & 3;             // 2M x 4N
  int mt = blockIdx.x, nt = blockIdx.y;        // 64 x 12
  int gm0 = mt * 128, gn0 = nt * 128;
  int l15 = lane & 15, q = lane >> 4, koff = q << 3;
  int nkt = (nt < 8) ? 48 : 32;                // h-region: skip zero-padded K
  f32x4 acc[4][2];
#pragma unroll
  for (int i = 0; i < 4; ++i)
#pragma unroll
    for (int j = 0; j < 2; ++j) acc[i][j] = f32x4{0.f, 0.f, 0.f, 0.f};

  auto stageAB = [&](int buf, int kt) {        // 2 loads/thread (1 A + 1 B)
    int blk = kt >> 4, kk = (kt & 15) << 5;
    const bf16_t* gA = (blk == 0 ? ain_b : blk == 1 ? aout_b : state_row_b)
                       + (size_t)gm0 * 512 + kk;
    bf16_t* base = (bf16_t*)(smem + buf * 16384);
    stage_lds16_128_w8(gA, 512, base);                                   // A 8KB
    stage_lds16_128_w8(Wall_t + (size_t)gn0 * 1536 + (kt << 5), 1536,
                       base + 4096);                                     // B 8KB
  };

  stageAB(0, 0);
  stageAB(1, 1);                               // 4 loads in flight per thread
  for (int kt = 0; kt < nkt; ++kt) {
    if (kt + 1 < nkt)
      asm volatile("s_waitcnt vmcnt(2)" ::: "memory");   // tile kt's loads done
    else
      asm volatile("s_waitcnt vmcnt(0)" ::: "memory");
    SCHED0(); SBAR(); SCHED0();                // publish tile kt to all waves
    const bf16_t* As = (const bf16_t*)(smem + (kt & 1) * 16384);
    const bf16_t* Bs = As + 4096;
    bf16x8 af[4], bfr[2];
#pragma unroll
    for (int i = 0; i < 4; ++i) af[i] = frag(As, wr * 64 + i * 16 + l15, koff);
#pragma unroll
    for (int j = 0; j < 2; ++j) bfr[j] = frag(Bs, wc * 32 + j * 16 + l15, koff);
#pragma unroll
    for (int i = 0; i < 4; ++i)
#pragma unroll
      for (int j = 0; j < 2; ++j)
        acc[i][j] = __builtin_amdgcn_mfma_f32_16x16x32_bf16(af[i], bfr[j], acc[i][j], 0, 0, 0);
    SCHED0(); SBAR(); SCHED0();                // all waves done reading this buf
    if (kt + 2 < nkt) stageAB(kt & 1, kt + 2); // refill; waited at iter kt+2
  }

  // coalesced epilogue: 4 passes of 128x32 via padded LDS transpose
  int region = nt >> 2;                        // 0:r 1:z 2:h
  int cn0 = gn0 - region * 512;                // local col base in [0,512)
  const float* bias = region == 0 ? b_r : region == 1 ? b_z : b_h;
#pragma unroll
  for (int p = 0; p < 4; ++p) {
    __syncthreads();
    if (wc == p) {                             // 2 waves (wr=0,1) cover 128 rows
#pragma unroll
      for (int i = 0; i < 4; ++i)
#pragma unroll
        for (int j = 0; j < 2; ++j)
#pragma unroll
          for (int rr = 0; rr < 4; ++rr)
            tr[(wr * 64 + i * 16 + q * 4 + rr) * 36 + j * 16 + l15] = acc[i][j][rr];
    }
    __syncthreads();
#pragma unroll
    for (int s = 0; s < 8; ++s) {
      int e = tid + (s << 9);                  // 0..4095
      int row = e >> 5, c = e & 31;
      int col = cn0 + (p << 5) + c;
      size_t idx = (size_t)(gm0 + row) * 512 + col;
      float x = tr[row * 36 + c] + bias[col];
      if (region == 0) {
        float rg = 1.0f / (1.0f + __expf(-x));
        rs_b[idx] = (bf16_t)(rg * (float)state_row_b[idx]);
      } else if (region == 1) {
        zb_b[idx] = (bf16_t)(1.0f / (1.0f + __expf(-x)));
      } else {
        hp_b[idx] = (bf16_t)x;
      }
    }
  }
}

// ---------------- small GEMM + GRU update: 64x128, 4 waves (r13) -----------
__global__ __launch_bounds__(256, 4) void k_gru(const bf16_t* __restrict__ rs_b,
                                                const bf16_t* __restrict__ Whb_t,
                                                const bf16_t* __restrict__ hp_b,
                                                const bf16_t* __restrict__ zb_b,
                                                float* __restrict__ state_f32,
                                                bf16_t* __restrict__ state_row_b) {
  __shared__ __align__(16) char smem[24576];   // 2 bufs x (A 4KB + B 8KB)
  float* tr = (float*)smem;                    // epilogue reuse (9KB)
  int mt = blockIdx.x, nt = blockIdx.y;        // 128 x 4
  int gm0 = mt * 64, gn0 = nt * 128;
  int lane = threadIdx.x & 63, wid = threadIdx.x >> 6;
  int wr = wid >> 1, wc = wid & 1;
  int l15 = lane & 15, q = lane >> 4, koff = q << 3;
  f32x4 acc[2][4];
#pragma unroll
  for (int i = 0; i < 2; ++i)
#pragma unroll
    for (int j = 0; j < 4; ++j) acc[i][j] = f32x4{0.f, 0.f, 0.f, 0.f};

  auto stageAB = [&](int buf, int kt) {        // 3 loads/thread
    bf16_t* base = (bf16_t*)(smem + buf * 12288);
    stage_lds16_64(rs_b + (size_t)gm0 * 512 + (kt << 5), 512, base);
    stage_lds16(Whb_t + (size_t)gn0 * 512 + (kt << 5), 512, base + 2048);
  };

  stageAB(0, 0);
  stageAB(1, 1);                               // 6 loads in flight
  for (int kt = 0; kt < 16; ++kt) {
    if (kt + 1 < 16)
      asm volatile("s_waitcnt vmcnt(3)" ::: "memory");
    else
      asm volatile("s_waitcnt vmcnt(0)" ::: "memory");
    SCHED0(); SBAR(); SCHED0();
    const bf16_t* As = (const bf16_t*)(smem + (kt & 1) * 12288);
    const bf16_t* Bs = As + 2048;
    bf16x8 af[2], bfr[4];
#pragma unroll
    for (int i = 0; i < 2; ++i) af[i] = frag(As, wr * 32 + i * 16 + l15, koff);
#pragma unroll
    for (int j = 0; j < 4; ++j) bfr[j] = frag(Bs, wc * 64 + j * 16 + l15, koff);
#pragma unroll
    for (int i = 0; i < 2; ++i)
#pragma unroll
      for (int j = 0; j < 4; ++j)
        acc[i][j] = __builtin_amdgcn_mfma_f32_16x16x32_bf16(af[i], bfr[j], acc[i][j], 0, 0, 0);
    SCHED0(); SBAR(); SCHED0();
    if (kt + 2 < 16) stageAB(kt & 1, kt + 2);
  }

  // coalesced epilogue: 4 passes of 64x32
#pragma unroll
  for (int p = 0; p < 4; ++p) {
    __syncthreads();
    if (wc == (p >> 1)) {
      int j0 = (p & 1) << 1;
#pragma unroll
      for (int jj = 0; jj < 2; ++jj) {
        int j = j0 + jj;
        int c = j * 16 + l15 - ((p & 1) << 5);
#pragma unroll
        for (int i = 0; i < 2; ++i)
#pragma unroll
          for (int rr = 0; rr < 4; ++rr) {
            int row = wr * 32 + i * 16 + q * 4 + rr;
            tr[row * 36 + c] = acc[i][j][rr];
          }
      }
    }
    __syncthreads();
#pragma unroll
    for (int s = 0; s < 8; ++s) {
      int e = threadIdx.x + (s << 8);                 // 0..2047
      int row = e >> 5, c = e & 31;
      int col = gn0 + (p << 5) + c;
      size_t idx = (size_t)(gm0 + row) * 512 + col;
      float x = tr[row * 36 + c] + (float)hp_b[idx];
      float hh = x > 0.0f ? x : 0.01f * x;
      float z = (float)zb_b[idx];
      float so = state_f32[idx];
      float sn = (1.0f - z) * so + z * hh;
      state_f32[idx] = sn;
      state_row_b[idx] = (bf16_t)sn;
    }
  }
}

// ---------------- bridge ----------------

__global__ __launch_bounds__(256) void k_join(const float* __restrict__ state_f32,
                                              bf16_t* __restrict__ join_b) {
  int idx = blockIdx.x * 256 + threadIdx.x;
  float s = 0.f;
#pragma unroll
  for (int b = 0; b < 32; ++b) s += state_f32[(size_t)b * 131072 + idx];
  join_b[idx] = (bf16_t)(s * (1.0f / 32.0f));
}

__global__ __launch_bounds__(256) void k_bridge(const bf16_t* __restrict__ join_b,
                                                const bf16_t* __restrict__ Wbh_t,
                                                const bf16_t* __restrict__ Wbc_t,
                                                const float* __restrict__ b_bh,
                                                const float* __restrict__ b_bc,
                                                float* __restrict__ out_h,
                                                float* __restrict__ out_c) {
  __shared__ bf16_t As[2][4096];
  __shared__ bf16_t Bs[2][4096];
  int mt = blockIdx.x, nt = blockIdx.y, hc = blockIdx.z;
  const bf16_t* Wt = hc ? Wbc_t : Wbh_t;
  const float* bias = hc ? b_bc : b_bh;
  float* dst = hc ? out_c : out_h;
  int gm0 = mt * 128, gn0 = nt * 128;
  int lane = threadIdx.x & 63, wid = threadIdx.x >> 6;
  int wr = wid >> 1, wc = wid & 1;
  int l15 = lane & 15, koff = (lane >> 4) << 3;
  f32x4 acc[4][4];
#pragma unroll
  for (int i = 0; i < 4; ++i)
#pragma unroll
    for (int j = 0; j < 4; ++j) acc[i][j] = f32x4{0.f, 0.f, 0.f, 0.f};
  auto stageAB = [&](int buf, int kt) {
    stage_lds16(join_b + (size_t)gm0 * 512 + (kt << 5), 512, As[buf]);
    stage_lds16(Wt + (size_t)gn0 * 512 + (kt << 5), 512, Bs[buf]);
  };
  stageAB(0, 0);
  __syncthreads();
  int cur = 0;
  for (int kt = 0; kt < 16; ++kt) {
    if (kt + 1 < 16) stageAB(cur ^ 1, kt + 1);
    bf16x8 af[4], bfr[4];
#pragma unroll
    for (int i = 0; i < 4; ++i) af[i] = frag(As[cur], wr * 64 + i * 16 + l15, koff);
#pragma unroll
    for (int j = 0; j < 4; ++j) bfr[j] = frag(Bs[cur], wc * 64 + j * 16 + l15, koff);
#pragma unroll
    for (int i = 0; i < 4; ++i)
#pragma unroll
      for (int j = 0; j < 4; ++j)
        acc[i][j] = __builtin_amdgcn_mfma_f32_16x16x32_bf16(af[i], bfr[j], acc[i][j], 0, 0, 0);
    __syncthreads();
    cur ^= 1;
  }
  int lr0 = (lane >> 4) << 2;
#pragma unroll
  for (int j = 0; j < 4; ++j) {
    int col = gn0 + wc * 64 + j * 16 + l15;
    float bv = bias[col];
#pragma unroll
    for (int i = 0; i < 4; ++i) {
#pragma unroll
      for (int r = 0; r < 4; ++r) {
        int row = gm0 + wr * 64 + i * 16 + lr0 + r;
        float v = acc[i][j][r] + bv;
        v = v > 0.f ? v : 0.f;
#pragma unroll
        for (int rep = 0; rep < 4; ++rep)
          dst[(size_t)rep * 131072 + (size_t)row * 512 + col] = v;
      }
    }
  }
}

// ---------------- launch ----------------

extern "C" void kernel_launch(void* const* d_in, const int* in_sizes, int n_in,
                              void* d_out, int out_size, void* d_ws, size_t ws_size,
                              hipStream_t stream) {
  const float* prop_state = (const float*)d_in[0];
  const float* edges = (const float*)d_in[1];
  const float* W_in = (const float*)d_in[2];
  const float* b_in = (const float*)d_in[3];
  const float* W_out = (const float*)d_in[4];
  const float* b_out = (const float*)d_in[5];
  const float* W_r = (const float*)d_in[6];
  const float* b_r = (const float*)d_in[7];
  const float* W_z = (const float*)d_in[8];
  const float* b_z = (const float*)d_in[9];
  const float* W_h = (const float*)d_in[10];
  const float* b_h = (const float*)d_in[11];
  const float* W_bh = (const float*)d_in[12];
  const float* b_bh = (const float*)d_in[13];
  const float* W_bc = (const float*)d_in[14];
  const float* b_bc = (const float*)d_in[15];

  float* out_state = (float*)d_out;          // 32*256*512 f32
  float* out_h = out_state + 4194304;        // 4*256*512
  float* out_c = out_h + 524288;

  char* ws = (char*)d_ws;
  size_t off = 0;
  auto alloc = [&](size_t bytes) -> void* {
    void* p = ws + off;
    off += (bytes + 255) & ~(size_t)255;
    return p;
  };
  unsigned short* nbr = (unsigned short*)alloc(16384ull * 64 * 2);
  uchar4* cnt4   = (uchar4*)alloc(16384ull * 4);
  float* wsum_in  = (float*)alloc(2048ull * 4);
  float* wsum_out = (float*)alloc(2048ull * 4);
  bf16_t* Wall_t = (bf16_t*)alloc(1536ull * 1536 * 2); // [n=1536][k=1536]
  bf16_t* Whb_t  = (bf16_t*)alloc(512ull * 512 * 2);   // W_h rows 1024:1536
  bf16_t* Wbh_t  = (bf16_t*)alloc(512ull * 512 * 2);
  bf16_t* Wbc_t  = (bf16_t*)alloc(512ull * 512 * 2);
  bf16_t* state_b = (bf16_t*)alloc(4194304ull * 2);    // row-major bf16 state
  bf16_t* ain_b  = (bf16_t*)alloc(4194304ull * 2);
  bf16_t* aout_b = (bf16_t*)alloc(4194304ull * 2);
  bf16_t* rs_b   = (bf16_t*)alloc(4194304ull * 2);
  bf16_t* zb_b   = (bf16_t*)alloc(4194304ull * 2);
  bf16_t* hp_b   = (bf16_t*)alloc(4194304ull * 2);
  bf16_t* join_b = (bf16_t*)alloc(131072ull * 2);
  if (off > ws_size) return;  // insufficient workspace -> output stays poisoned

  // prep
  k_build_idx<<<4096, 256, 0, stream>>>(edges, nbr, cnt4);
  k_rowsum<<<512, 256, 0, stream>>>(W_in, wsum_in, 2048);
  k_rowsum<<<512, 256, 0, stream>>>(W_out, wsum_out, 2048);
  k_prep_wall<<<dim3(16, 48, 3), 256, 0, stream>>>(W_r, W_z, W_h, Wall_t);
  k_prep_small<<<dim3(16, 16, 3), 256, 0, stream>>>(W_h + 1024 * 512, W_bh, W_bc,
                                                    Whb_t, Wbh_t, Wbc_t);
  k_state_init<<<4096, 256, 0, stream>>>(prop_state, out_state, state_b, 1048576);

  // 4 propagation steps
  for (int step = 0; step < 4; ++step) {
    k_agg_sparse<<<4096, 256, 0, stream>>>(nbr, cnt4, state_b, wsum_in, wsum_out,
                                           b_in, b_out, ain_b, aout_b);
    k_gates<<<dim3(64, 12), 512, 0, stream>>>(ain_b, aout_b, state_b, Wall_t,
                                              b_r, b_z, b_h, rs_b, zb_b, hp_b);
    k_gru<<<dim3(128, 4), 256, 0, stream>>>(rs_b, Whb_t, hp_b, zb_b,
                                            out_state, state_b);
  }

  // bridge
  k_join<<<512, 256, 0, stream>>>(out_state, join_b);
  k_bridge<<<dim3(2, 4, 2), 256, 0, stream>>>(join_b, Wbh_t, Wbc_t, b_bh, b_bc, out_h, out_c);
}

// Round 18
// 482.019 us; speedup vs baseline: 1.1186x; 1.0198x over previous
//
#include <hip/hip_runtime.h>
#include <math.h>

// GGNN encoder. B=32, N=256, D=512, E=4, N_STEPS=4.  [r13 GEMMs + fused prep]
// einsum('bnd,edh->bend') is DIAGONAL in d -> ins/outs are elementwise
// scalings. Edges 2% sparse -> sparse gather aggregation.
// Gates: wide GEMM [ain|aout|state](8192x1536) @ W_all(1536x1536), 128x128
// tile, 8 waves (wave tile 64x32), BK=32, 24 waves/CU (measured optimum:
// 58us, 593 TF). k_gru: 64x128, 4 waves. All prep fused into ONE launch.

typedef __bf16 bf16_t;
typedef __bf16 bf16x8 __attribute__((ext_vector_type(8)));
typedef __bf16 bf16x4_t __attribute__((ext_vector_type(4)));
typedef float f32x4 __attribute__((ext_vector_type(4)));

#define SBAR() __builtin_amdgcn_s_barrier()
#define SCHED0() __builtin_amdgcn_sched_barrier(0)

// ---------------- staging: global -> LDS ----------------
// 128 rows x 32 k, 256 threads (4 waves), 2 loads/thread
__device__ __forceinline__ void stage_lds16(const bf16_t* __restrict__ g, int ld,
                                            bf16_t* __restrict__ s) {
  int wave = threadIdx.x >> 6;
  int lane = threadIdx.x & 63;
  int rsub = lane >> 2;          // 0..15
  int k0 = (lane & 3) << 3;      // 0,8,16,24
#pragma unroll
  for (int i = 0; i < 2; ++i) {
    int c = wave + (i << 2);     // chunk 0..7 (16 rows each)
    const bf16_t* gp = g + (size_t)((c << 4) + rsub) * ld + k0;
    __builtin_amdgcn_global_load_lds(
        (const __attribute__((address_space(1))) void*)gp,
        (__attribute__((address_space(3))) void*)(s + (c << 9)), 16, 0, 0);
  }
}

// 64 rows x 32 k, 256 threads, 1 load/thread
__device__ __forceinline__ void stage_lds16_64(const bf16_t* __restrict__ g, int ld,
                                               bf16_t* __restrict__ s) {
  int wave = threadIdx.x >> 6;
  int lane = threadIdx.x & 63;
  int rsub = lane >> 2;
  int k0 = (lane & 3) << 3;
  const bf16_t* gp = g + (size_t)((wave << 4) + rsub) * ld + k0;
  __builtin_amdgcn_global_load_lds(
      (const __attribute__((address_space(1))) void*)gp,
      (__attribute__((address_space(3))) void*)(s + (wave << 9)), 16, 0, 0);
}

// 128 rows x 32 k, 512 threads (8 waves), 1 load/thread
__device__ __forceinline__ void stage_lds16_128_w8(const bf16_t* __restrict__ g, int ld,
                                                   bf16_t* __restrict__ s) {
  int wave = threadIdx.x >> 6;   // 0..7
  int lane = threadIdx.x & 63;
  int rsub = lane >> 2;
  int k0 = (lane & 3) << 3;
  const bf16_t* gp = g + (size_t)((wave << 4) + rsub) * ld + k0;
  __builtin_amdgcn_global_load_lds(
      (const __attribute__((address_space(1))) void*)gp,
      (__attribute__((address_space(3))) void*)(s + (wave << 9)), 16, 0, 0);
}

__device__ __forceinline__ bf16x8 frag(const bf16_t* s, int r, int koff) {
  return *reinterpret_cast<const bf16x8*>(s + (r << 5) + koff);
}

// ---------------- fused prep: one launch, blockIdx.x-range dispatch --------
// [0,4096)      build_idx (one wave per (b,io,n) x4)
// [4096,4608)   rowsum W_in
// [4608,5120)   rowsum W_out
// [5120,7424)   Wall_t transpose (16 x 48 x 3)
// [7424,8192)   Whb/Wbh/Wbc transpose (16 x 16 x 3)
// [8192,12288)  state init
__global__ __launch_bounds__(256) void k_prep_all(
    const float* __restrict__ edges, unsigned short* __restrict__ nbr,
    uchar4* __restrict__ cnt4,
    const float* __restrict__ W_in, const float* __restrict__ W_out,
    float* __restrict__ wsum_in, float* __restrict__ wsum_out,
    const float* __restrict__ W_r, const float* __restrict__ W_z,
    const float* __restrict__ W_h, bf16_t* __restrict__ Wall_t,
    const float* __restrict__ W_bh, const float* __restrict__ W_bc,
    bf16_t* __restrict__ Whb_t, bf16_t* __restrict__ Wbh_t,
    bf16_t* __restrict__ Wbc_t,
    const float* __restrict__ prop_state, float* __restrict__ out_state,
    bf16_t* __restrict__ state_b) {
  __shared__ float tile[32][33];
  int bid = blockIdx.x;
  int wid = threadIdx.x >> 6, lane = threadIdx.x & 63;

  if (bid < 4096) {
    // ---- build_idx ----
    int W = bid * 4 + wid;               // 0..16383
    int b = W >> 9, io = (W >> 8) & 1, n = W & 255;
    const float* p = edges + (size_t)(b * 256 + n) * 2048 + io * 1024;
    unsigned short* list = nbr + (size_t)W * 64;
    int base = 0;
    int ends[4];
#pragma unroll
    for (int e = 0; e < 4; ++e) {
#pragma unroll
      for (int ch = 0; ch < 4; ++ch) {
        int c = e * 256 + ch * 64 + lane;
        float v = p[c];
        unsigned long long mask = __ballot(v != 0.0f);
        int before = __popcll(mask & ((1ull << lane) - 1ull));
        if (v != 0.0f && (base + before) < 64) list[base + before] = (unsigned short)c;
        base += __popcll(mask);
      }
      ends[e] = base < 64 ? base : 64;
    }
    if (lane == 0)
      cnt4[W] = make_uchar4((unsigned char)ends[0], (unsigned char)ends[1],
                            (unsigned char)ends[2], (unsigned char)ends[3]);
  } else if (bid < 5120) {
    // ---- rowsum (W_in or W_out) ----
    const float* Wsrc = bid < 4608 ? W_in : W_out;
    float* wsum = bid < 4608 ? wsum_in : wsum_out;
    int row = (bid - (bid < 4608 ? 4096 : 4608)) * 4 + wid;   // < 2048
    const float4* p = reinterpret_cast<const float4*>(Wsrc + (size_t)row * 512);
    float s = 0.f;
#pragma unroll
    for (int i = 0; i < 2; ++i) {
      float4 v = p[lane + i * 64];
      s += v.x + v.y + v.z + v.w;
    }
#pragma unroll
    for (int off = 32; off > 0; off >>= 1) s += __shfl_down(s, off, 64);
    if (lane == 0) wsum[row] = s;
  } else if (bid < 7424) {
    // ---- Wall_t transpose: z=0 W_r, z=1 W_z, z=2 W_h (top 1024, zero-pad) --
    int r = bid - 5120;                   // 0..2303
    int bx = r & 15, by = (r >> 4) % 48, z = r / 768;
    const float* src = z == 0 ? W_r : z == 1 ? W_z : W_h;
    int Ksrc = z == 2 ? 1024 : 1536;
    bf16_t* d = Wall_t + (size_t)(z * 512) * 1536;
    int tx = threadIdx.x & 31, ty = threadIdx.x >> 5;
    int n0 = bx * 32, k0 = by * 32;
    if (k0 >= Ksrc) {
#pragma unroll
      for (int i = 0; i < 4; ++i)
        d[(size_t)(n0 + ty + i * 8) * 1536 + k0 + tx] = (bf16_t)0.0f;
      return;
    }
#pragma unroll
    for (int i = 0; i < 4; ++i)
      tile[ty + i * 8][tx] = src[(size_t)(k0 + ty + i * 8) * 512 + n0 + tx];
    __syncthreads();
#pragma unroll
    for (int i = 0; i < 4; ++i)
      d[(size_t)(n0 + ty + i * 8) * 1536 + k0 + tx] = (bf16_t)tile[tx][ty + i * 8];
  } else if (bid < 8192) {
    // ---- small transposes: z=0 Whb (W_h rows 1024:), z=1 Wbh, z=2 Wbc ----
    int r = bid - 7424;                   // 0..767
    int bx = r & 15, by = (r >> 4) & 15, z = r >> 8;
    const float* src = z == 0 ? (W_h + 1024 * 512) : z == 1 ? W_bh : W_bc;
    bf16_t* dst = z == 0 ? Whb_t : z == 1 ? Wbh_t : Wbc_t;
    int tx = threadIdx.x & 31, ty = threadIdx.x >> 5;
    int n0 = bx * 32, k0 = by * 32;
#pragma unroll
    for (int i = 0; i < 4; ++i)
      tile[ty + i * 8][tx] = src[(size_t)(k0 + ty + i * 8) * 512 + n0 + tx];
    __syncthreads();
#pragma unroll
    for (int i = 0; i < 4; ++i)
      dst[(size_t)(n0 + ty + i * 8) * 512 + k0 + tx] = (bf16_t)tile[tx][ty + i * 8];
  } else {
    // ---- state init ----
    int i = (bid - 8192) * 256 + threadIdx.x;   // < 1048576
    float4 v = reinterpret_cast<const float4*>(prop_state)[i];
    reinterpret_cast<float4*>(out_state)[i] = v;
    bf16x4_t o;
    o[0] = (bf16_t)v.x; o[1] = (bf16_t)v.y; o[2] = (bf16_t)v.z; o[3] = (bf16_t)v.w;
    *reinterpret_cast<bf16x4_t*>(state_b + (size_t)i * 4) = o;
  }
}

// ---------------- sparse aggregation ----------------
__global__ __launch_bounds__(256) void k_agg_sparse(const unsigned short* __restrict__ nbr,
                                                    const uchar4* __restrict__ cnt4,
                                                    const bf16_t* __restrict__ state_b,
                                                    const float* __restrict__ wsum_in,
                                                    const float* __restrict__ wsum_out,
                                                    const float* __restrict__ b_in,
                                                    const float* __restrict__ b_out,
                                                    bf16_t* __restrict__ ain_b,
                                                    bf16_t* __restrict__ aout_b) {
  int wid = threadIdx.x >> 6, lane = threadIdx.x & 63;
  int W = blockIdx.x * 4 + wid;          // 0..16383
  int b = W >> 9, io = (W >> 8) & 1, n = W & 255;
  const float* wsel = io ? wsum_out : wsum_in;
  const float* bsel = io ? b_out : b_in;
  int d0 = lane << 3;
  float w[4][8], bi[4][8];
#pragma unroll
  for (int e = 0; e < 4; ++e) {
#pragma unroll
    for (int t = 0; t < 8; t += 4) {
      float4 v = *reinterpret_cast<const float4*>(wsel + e * 512 + d0 + t);
      w[e][t] = v.x; w[e][t + 1] = v.y; w[e][t + 2] = v.z; w[e][t + 3] = v.w;
      float4 u = *reinterpret_cast<const float4*>(bsel + e * 512 + d0 + t);
      bi[e][t] = u.x; bi[e][t + 1] = u.y; bi[e][t + 2] = u.z; bi[e][t + 3] = u.w;
    }
  }
  int mycode = nbr[(size_t)W * 64 + lane];
  uchar4 ce = cnt4[W];
  float acc[8];
#pragma unroll
  for (int t = 0; t < 8; ++t) acc[t] = 0.f;
  const bf16_t* Sb = state_b + ((size_t)b << 17) + d0;
  int start = 0;
#pragma unroll
  for (int e = 0; e < 4; ++e) {
    int end = (e == 0) ? ce.x : (e == 1) ? ce.y : (e == 2) ? ce.z : ce.w;
    float fc = (float)(end - start);
#pragma unroll
    for (int t = 0; t < 8; ++t) acc[t] += fc * bi[e][t];
    for (int j = start; j < end; ++j) {
      int c = __shfl(mycode, j, 64);
      int m = c & 255;
      bf16x8 s = *reinterpret_cast<const bf16x8*>(Sb + ((size_t)m << 9));
#pragma unroll
      for (int t = 0; t < 8; ++t) acc[t] += (float)s[t] * w[e][t];
    }
    start = end;
  }
  bf16x8 o;
#pragma unroll
  for (int t = 0; t < 8; ++t) o[t] = (bf16_t)acc[t];
  bf16_t* dst = io ? aout_b : ain_b;
  *reinterpret_cast<bf16x8*>(dst + (size_t)(b * 256 + n) * 512 + d0) = o;
}

// ---------------- wide gate GEMM: 128x128, 8 waves, BK=32 (r13 optimum) ----
// grid (64, 12); nt 0-3: r -> rs_b ; 4-7: z -> zb_b ; 8-11: h (K=1024) -> hp_b.
// Wave tile 64x32: wr = wid>>2, wc = wid&3. 24 waves/CU.
__global__ __launch_bounds__(512, 6) void k_gates(const bf16_t* __restrict__ ain_b,
                                                  const bf16_t* __restrict__ aout_b,
                                                  const bf16_t* __restrict__ state_row_b,
                                                  const bf16_t* __restrict__ Wall_t,
                                                  const float* __restrict__ b_r,
                                                  const float* __restrict__ b_z,
                                                  const float* __restrict__ b_h,
                                                  bf16_t* __restrict__ rs_b,
                                                  bf16_t* __restrict__ zb_b,
                                                  bf16_t* __restrict__ hp_b) {
  __shared__ __align__(16) char smem[32768];   // 2 bufs x (A 8KB + B 8KB)
  float* tr = (float*)smem;                    // epilogue reuse [128][36] = 18KB
  int tid = threadIdx.x;
  int lane = tid & 63, wid = tid >> 6;         // 8 waves
  int wr = wid >> 2, wc = wid & 3;             // 2M x 4N
  int mt = blockIdx.x, nt = blockIdx.y;        // 64 x 12
  int gm0 = mt * 128, gn0 = nt * 128;
  int l15 = lane & 15, q = lane >> 4, koff = q << 3;
  int nkt = (nt < 8) ? 48 : 32;                // h-region: skip zero-padded K
  f32x4 acc[4][2];
#pragma unroll
  for (int i = 0; i < 4; ++i)
#pragma unroll
    for (int j = 0; j < 2; ++j) acc[i][j] = f32x4{0.f, 0.f, 0.f, 0.f};

  auto stageAB = [&](int buf, int kt) {        // 2 loads/thread (1 A + 1 B)
    int blk = kt >> 4, kk = (kt & 15) << 5;
    const bf16_t* gA = (blk == 0 ? ain_b : blk == 1 ? aout_b : state_row_b)
                       + (size_t)gm0 * 512 + kk;
    bf16_t* base = (bf16_t*)(smem + buf * 16384);
    stage_lds16_128_w8(gA, 512, base);                                   // A 8KB
    stage_lds16_128_w8(Wall_t + (size_t)gn0 * 1536 + (kt << 5), 1536,
                       base + 4096);                                     // B 8KB
  };

  stageAB(0, 0);
  stageAB(1, 1);                               // 4 loads in flight per thread
  for (int kt = 0; kt < nkt; ++kt) {
    if (kt + 1 < nkt)
      asm volatile("s_waitcnt vmcnt(2)" ::: "memory");   // tile kt's loads done
    else
      asm volatile("s_waitcnt vmcnt(0)" ::: "memory");
    SCHED0(); SBAR(); SCHED0();                // publish tile kt to all waves
    const bf16_t* As = (const bf16_t*)(smem + (kt & 1) * 16384);
    const bf16_t* Bs = As + 4096;
    bf16x8 af[4], bfr[2];
#pragma unroll
    for (int i = 0; i < 4; ++i) af[i] = frag(As, wr * 64 + i * 16 + l15, koff);
#pragma unroll
    for (int j = 0; j < 2; ++j) bfr[j] = frag(Bs, wc * 32 + j * 16 + l15, koff);
#pragma unroll
    for (int i = 0; i < 4; ++i)
#pragma unroll
      for (int j = 0; j < 2; ++j)
        acc[i][j] = __builtin_amdgcn_mfma_f32_16x16x32_bf16(af[i], bfr[j], acc[i][j], 0, 0, 0);
    SCHED0(); SBAR(); SCHED0();                // all waves done reading this buf
    if (kt + 2 < nkt) stageAB(kt & 1, kt + 2); // refill; waited at iter kt+2
  }

  // coalesced epilogue: 4 passes of 128x32 via padded LDS transpose
  int region = nt >> 2;                        // 0:r 1:z 2:h
  int cn0 = gn0 - region * 512;                // local col base in [0,512)
  const float* bias = region == 0 ? b_r : region == 1 ? b_z : b_h;
#pragma unroll
  for (int p = 0; p < 4; ++p) {
    __syncthreads();
    if (wc == p) {                             // 2 waves (wr=0,1) cover 128 rows
#pragma unroll
      for (int i = 0; i < 4; ++i)
#pragma unroll
        for (int j = 0; j < 2; ++j)
#pragma unroll
          for (int rr = 0; rr < 4; ++rr)
            tr[(wr * 64 + i * 16 + q * 4 + rr) * 36 + j * 16 + l15] = acc[i][j][rr];
    }
    __syncthreads();
#pragma unroll
    for (int s = 0; s < 8; ++s) {
      int e = tid + (s << 9);                  // 0..4095
      int row = e >> 5, c = e & 31;
      int col = cn0 + (p << 5) + c;
      size_t idx = (size_t)(gm0 + row) * 512 + col;
      float x = tr[row * 36 + c] + bias[col];
      if (region == 0) {
        float rg = 1.0f / (1.0f + __expf(-x));
        rs_b[idx] = (bf16_t)(rg * (float)state_row_b[idx]);
      } else if (region == 1) {
        zb_b[idx] = (bf16_t)(1.0f / (1.0f + __expf(-x)));
      } else {
        hp_b[idx] = (bf16_t)x;
      }
    }
  }
}

// ---------------- small GEMM + GRU update: 64x128, 4 waves (r13) -----------
__global__ __launch_bounds__(256, 4) void k_gru(const bf16_t* __restrict__ rs_b,
                                                const bf16_t* __restrict__ Whb_t,
                                                const bf16_t* __restrict__ hp_b,
                                                const bf16_t* __restrict__ zb_b,
                                                float* __restrict__ state_f32,
                                                bf16_t* __restrict__ state_row_b) {
  __shared__ __align__(16) char smem[24576];   // 2 bufs x (A 4KB + B 8KB)
  float* tr = (float*)smem;                    // epilogue reuse (9KB)
  int mt = blockIdx.x, nt = blockIdx.y;        // 128 x 4
  int gm0 = mt * 64, gn0 = nt * 128;
  int lane = threadIdx.x & 63, wid = threadIdx.x >> 6;
  int wr = wid >> 1, wc = wid & 1;
  int l15 = lane & 15, q = lane >> 4, koff = q << 3;
  f32x4 acc[2][4];
#pragma unroll
  for (int i = 0; i < 2; ++i)
#pragma unroll
    for (int j = 0; j < 4; ++j) acc[i][j] = f32x4{0.f, 0.f, 0.f, 0.f};

  auto stageAB = [&](int buf, int kt) {        // 3 loads/thread
    bf16_t* base = (bf16_t*)(smem + buf * 12288);
    stage_lds16_64(rs_b + (size_t)gm0 * 512 + (kt << 5), 512, base);
    stage_lds16(Whb_t + (size_t)gn0 * 512 + (kt << 5), 512, base + 2048);
  };

  stageAB(0, 0);
  stageAB(1, 1);                               // 6 loads in flight
  for (int kt = 0; kt < 16; ++kt) {
    if (kt + 1 < 16)
      asm volatile("s_waitcnt vmcnt(3)" ::: "memory");
    else
      asm volatile("s_waitcnt vmcnt(0)" ::: "memory");
    SCHED0(); SBAR(); SCHED0();
    const bf16_t* As = (const bf16_t*)(smem + (kt & 1) * 12288);
    const bf16_t* Bs = As + 2048;
    bf16x8 af[2], bfr[4];
#pragma unroll
    for (int i = 0; i < 2; ++i) af[i] = frag(As, wr * 32 + i * 16 + l15, koff);
#pragma unroll
    for (int j = 0; j < 4; ++j) bfr[j] = frag(Bs, wc * 64 + j * 16 + l15, koff);
#pragma unroll
    for (int i = 0; i < 2; ++i)
#pragma unroll
      for (int j = 0; j < 4; ++j)
        acc[i][j] = __builtin_amdgcn_mfma_f32_16x16x32_bf16(af[i], bfr[j], acc[i][j], 0, 0, 0);
    SCHED0(); SBAR(); SCHED0();
    if (kt + 2 < 16) stageAB(kt & 1, kt + 2);
  }

  // coalesced epilogue: 4 passes of 64x32
#pragma unroll
  for (int p = 0; p < 4; ++p) {
    __syncthreads();
    if (wc == (p >> 1)) {
      int j0 = (p & 1) << 1;
#pragma unroll
      for (int jj = 0; jj < 2; ++jj) {
        int j = j0 + jj;
        int c = j * 16 + l15 - ((p & 1) << 5);
#pragma unroll
        for (int i = 0; i < 2; ++i)
#pragma unroll
          for (int rr = 0; rr < 4; ++rr) {
            int row = wr * 32 + i * 16 + q * 4 + rr;
            tr[row * 36 + c] = acc[i][j][rr];
          }
      }
    }
    __syncthreads();
#pragma unroll
    for (int s = 0; s < 8; ++s) {
      int e = threadIdx.x + (s << 8);                 // 0..2047
      int row = e >> 5, c = e & 31;
      int col = gn0 + (p << 5) + c;
      size_t idx = (size_t)(gm0 + row) * 512 + col;
      float x = tr[row * 36 + c] + (float)hp_b[idx];
      float hh = x > 0.0f ? x : 0.01f * x;
      float z = (float)zb_b[idx];
      float so = state_f32[idx];
      float sn = (1.0f - z) * so + z * hh;
      state_f32[idx] = sn;
      state_row_b[idx] = (bf16_t)sn;
    }
  }
}

// ---------------- bridge ----------------

__global__ __launch_bounds__(256) void k_join(const float* __restrict__ state_f32,
                                              bf16_t* __restrict__ join_b) {
  int idx = blockIdx.x * 256 + threadIdx.x;
  float s = 0.f;
#pragma unroll
  for (int b = 0; b < 32; ++b) s += state_f32[(size_t)b * 131072 + idx];
  join_b[idx] = (bf16_t)(s * (1.0f / 32.0f));
}

__global__ __launch_bounds__(256) void k_bridge(const bf16_t* __restrict__ join_b,
                                                const bf16_t* __restrict__ Wbh_t,
                                                const bf16_t* __restrict__ Wbc_t,
                                                const float* __restrict__ b_bh,
                                                const float* __restrict__ b_bc,
                                                float* __restrict__ out_h,
                                                float* __restrict__ out_c) {
  __shared__ bf16_t As[2][4096];
  __shared__ bf16_t Bs[2][4096];
  int mt = blockIdx.x, nt = blockIdx.y, hc = blockIdx.z;
  const bf16_t* Wt = hc ? Wbc_t : Wbh_t;
  const float* bias = hc ? b_bc : b_bh;
  float* dst = hc ? out_c : out_h;
  int gm0 = mt * 128, gn0 = nt * 128;
  int lane = threadIdx.x & 63, wid = threadIdx.x >> 6;
  int wr = wid >> 1, wc = wid & 1;
  int l15 = lane & 15, koff = (lane >> 4) << 3;
  f32x4 acc[4][4];
#pragma unroll
  for (int i = 0; i < 4; ++i)
#pragma unroll
    for (int j = 0; j < 4; ++j) acc[i][j] = f32x4{0.f, 0.f, 0.f, 0.f};
  auto stageAB = [&](int buf, int kt) {
    stage_lds16(join_b + (size_t)gm0 * 512 + (kt << 5), 512, As[buf]);
    stage_lds16(Wt + (size_t)gn0 * 512 + (kt << 5), 512, Bs[buf]);
  };
  stageAB(0, 0);
  __syncthreads();
  int cur = 0;
  for (int kt = 0; kt < 16; ++kt) {
    if (kt + 1 < 16) stageAB(cur ^ 1, kt + 1);
    bf16x8 af[4], bfr[4];
#pragma unroll
    for (int i = 0; i < 4; ++i) af[i] = frag(As[cur], wr * 64 + i * 16 + l15, koff);
#pragma unroll
    for (int j = 0; j < 4; ++j) bfr[j] = frag(Bs[cur], wc * 64 + j * 16 + l15, koff);
#pragma unroll
    for (int i = 0; i < 4; ++i)
#pragma unroll
      for (int j = 0; j < 4; ++j)
        acc[i][j] = __builtin_amdgcn_mfma_f32_16x16x32_bf16(af[i], bfr[j], acc[i][j], 0, 0, 0);
    __syncthreads();
    cur ^= 1;
  }
  int lr0 = (lane >> 4) << 2;
#pragma unroll
  for (int j = 0; j < 4; ++j) {
    int col = gn0 + wc * 64 + j * 16 + l15;
    float bv = bias[col];
#pragma unroll
    for (int i = 0; i < 4; ++i) {
#pragma unroll
      for (int r = 0; r < 4; ++r) {
        int row = gm0 + wr * 64 + i * 16 + lr0 + r;
        float v = acc[i][j][r] + bv;
        v = v > 0.f ? v : 0.f;
#pragma unroll
        for (int rep = 0; rep < 4; ++rep)
          dst[(size_t)rep * 131072 + (size_t)row * 512 + col] = v;
      }
    }
  }
}

// ---------------- launch ----------------

extern "C" void kernel_launch(void* const* d_in, const int* in_sizes, int n_in,
                              void* d_out, int out_size, void* d_ws, size_t ws_size,
                              hipStream_t stream) {
  const float* prop_state = (const float*)d_in[0];
  const float* edges = (const float*)d_in[1];
  const float* W_in = (const float*)d_in[2];
  const float* b_in = (const float*)d_in[3];
  const float* W_out = (const float*)d_in[4];
  const float* b_out = (const float*)d_in[5];
  const float* W_r = (const float*)d_in[6];
  const float* b_r = (const float*)d_in[7];
  const float* W_z = (const float*)d_in[8];
  const float* b_z = (const float*)d_in[9];
  const float* W_h = (const float*)d_in[10];
  const float* b_h = (const float*)d_in[11];
  const float* W_bh = (const float*)d_in[12];
  const float* b_bh = (const float*)d_in[13];
  const float* W_bc = (const float*)d_in[14];
  const float* b_bc = (const float*)d_in[15];

  float* out_state = (float*)d_out;          // 32*256*512 f32
  float* out_h = out_state + 4194304;        // 4*256*512
  float* out_c = out_h + 524288;

  char* ws = (char*)d_ws;
  size_t off = 0;
  auto alloc = [&](size_t bytes) -> void* {
    void* p = ws + off;
    off += (bytes + 255) & ~(size_t)255;
    return p;
  };
  unsigned short* nbr = (unsigned short*)alloc(16384ull * 64 * 2);
  uchar4* cnt4   = (uchar4*)alloc(16384ull * 4);
  float* wsum_in  = (float*)alloc(2048ull * 4);
  float* wsum_out = (float*)alloc(2048ull * 4);
  bf16_t* Wall_t = (bf16_t*)alloc(1536ull * 1536 * 2); // [n=1536][k=1536]
  bf16_t* Whb_t  = (bf16_t*)alloc(512ull * 512 * 2);   // W_h rows 1024:1536
  bf16_t* Wbh_t  = (bf16_t*)alloc(512ull * 512 * 2);
  bf16_t* Wbc_t  = (bf16_t*)alloc(512ull * 512 * 2);
  bf16_t* state_b = (bf16_t*)alloc(4194304ull * 2);    // row-major bf16 state
  bf16_t* ain_b  = (bf16_t*)alloc(4194304ull * 2);
  bf16_t* aout_b = (bf16_t*)alloc(4194304ull * 2);
  bf16_t* rs_b   = (bf16_t*)alloc(4194304ull * 2);
  bf16_t* zb_b   = (bf16_t*)alloc(4194304ull * 2);
  bf16_t* hp_b   = (bf16_t*)alloc(4194304ull * 2);
  bf16_t* join_b = (bf16_t*)alloc(131072ull * 2);
  if (off > ws_size) return;  // insufficient workspace -> output stays poisoned

  // fused prep: one launch, all independent prep tasks overlapped
  k_prep_all<<<12288, 256, 0, stream>>>(edges, nbr, cnt4,
                                        W_in, W_out, wsum_in, wsum_out,
                                        W_r, W_z, W_h, Wall_t,
                                        W_bh, W_bc, Whb_t, Wbh_t, Wbc_t,
                                        prop_state, out_state, state_b);

  // 4 propagation steps
  for (int step = 0; step < 4; ++step) {
    k_agg_sparse<<<4096, 256, 0, stream>>>(nbr, cnt4, state_b, wsum_in, wsum_out,
                                           b_in, b_out, ain_b, aout_b);
    k_gates<<<dim3(64, 12), 512, 0, stream>>>(ain_b, aout_b, state_b, Wall_t,
                                              b_r, b_z, b_h, rs_b, zb_b, hp_b);
    k_gru<<<dim3(128, 4), 256, 0, stream>>>(rs_b, Whb_t, hp_b, zb_b,
                                            out_state, state_b);
  }

  // bridge
  k_join<<<512, 256, 0, stream>>>(out_state, join_b);
  k_bridge<<<dim3(2, 4, 2), 256, 0, stream>>>(join_b, Wbh_t, Wbc_t, b_bh, b_bc, out_h, out_c);
}

// Round 19
// 481.488 us; speedup vs baseline: 1.1198x; 1.0011x over previous
//
#include <hip/hip_runtime.h>
#include <math.h>

// GGNN encoder. B=32, N=256, D=512, E=4, N_STEPS=4.  [FINAL: r13 GEMMs + fused prep]
// einsum('bnd,edh->bend') is DIAGONAL in d -> ins/outs are elementwise
// scalings. Edges 2% sparse -> sparse gather aggregation.
// Gates: wide GEMM [ain|aout|state](8192x1536) @ W_all(1536x1536), 128x128
// tile, 8 waves (wave tile 64x32), BK=32, 24 waves/CU (measured optimum:
// 58us, 593 TF). k_gru: 64x128, 4 waves. All prep fused into ONE launch.

typedef __bf16 bf16_t;
typedef __bf16 bf16x8 __attribute__((ext_vector_type(8)));
typedef __bf16 bf16x4_t __attribute__((ext_vector_type(4)));
typedef float f32x4 __attribute__((ext_vector_type(4)));

#define SBAR() __builtin_amdgcn_s_barrier()
#define SCHED0() __builtin_amdgcn_sched_barrier(0)

// ---------------- staging: global -> LDS ----------------
// 128 rows x 32 k, 256 threads (4 waves), 2 loads/thread
__device__ __forceinline__ void stage_lds16(const bf16_t* __restrict__ g, int ld,
                                            bf16_t* __restrict__ s) {
  int wave = threadIdx.x >> 6;
  int lane = threadIdx.x & 63;
  int rsub = lane >> 2;          // 0..15
  int k0 = (lane & 3) << 3;      // 0,8,16,24
#pragma unroll
  for (int i = 0; i < 2; ++i) {
    int c = wave + (i << 2);     // chunk 0..7 (16 rows each)
    const bf16_t* gp = g + (size_t)((c << 4) + rsub) * ld + k0;
    __builtin_amdgcn_global_load_lds(
        (const __attribute__((address_space(1))) void*)gp,
        (__attribute__((address_space(3))) void*)(s + (c << 9)), 16, 0, 0);
  }
}

// 64 rows x 32 k, 256 threads, 1 load/thread
__device__ __forceinline__ void stage_lds16_64(const bf16_t* __restrict__ g, int ld,
                                               bf16_t* __restrict__ s) {
  int wave = threadIdx.x >> 6;
  int lane = threadIdx.x & 63;
  int rsub = lane >> 2;
  int k0 = (lane & 3) << 3;
  const bf16_t* gp = g + (size_t)((wave << 4) + rsub) * ld + k0;
  __builtin_amdgcn_global_load_lds(
      (const __attribute__((address_space(1))) void*)gp,
      (__attribute__((address_space(3))) void*)(s + (wave << 9)), 16, 0, 0);
}

// 128 rows x 32 k, 512 threads (8 waves), 1 load/thread
__device__ __forceinline__ void stage_lds16_128_w8(const bf16_t* __restrict__ g, int ld,
                                                   bf16_t* __restrict__ s) {
  int wave = threadIdx.x >> 6;   // 0..7
  int lane = threadIdx.x & 63;
  int rsub = lane >> 2;
  int k0 = (lane & 3) << 3;
  const bf16_t* gp = g + (size_t)((wave << 4) + rsub) * ld + k0;
  __builtin_amdgcn_global_load_lds(
      (const __attribute__((address_space(1))) void*)gp,
      (__attribute__((address_space(3))) void*)(s + (wave << 9)), 16, 0, 0);
}

__device__ __forceinline__ bf16x8 frag(const bf16_t* s, int r, int koff) {
  return *reinterpret_cast<const bf16x8*>(s + (r << 5) + koff);
}

// ---------------- fused prep: one launch, blockIdx.x-range dispatch --------
// [0,4096)      build_idx (one wave per (b,io,n) x4)
// [4096,4608)   rowsum W_in
// [4608,5120)   rowsum W_out
// [5120,7424)   Wall_t transpose (16 x 48 x 3)
// [7424,8192)   Whb/Wbh/Wbc transpose (16 x 16 x 3)
// [8192,12288)  state init
__global__ __launch_bounds__(256) void k_prep_all(
    const float* __restrict__ edges, unsigned short* __restrict__ nbr,
    uchar4* __restrict__ cnt4,
    const float* __restrict__ W_in, const float* __restrict__ W_out,
    float* __restrict__ wsum_in, float* __restrict__ wsum_out,
    const float* __restrict__ W_r, const float* __restrict__ W_z,
    const float* __restrict__ W_h, bf16_t* __restrict__ Wall_t,
    const float* __restrict__ W_bh, const float* __restrict__ W_bc,
    bf16_t* __restrict__ Whb_t, bf16_t* __restrict__ Wbh_t,
    bf16_t* __restrict__ Wbc_t,
    const float* __restrict__ prop_state, float* __restrict__ out_state,
    bf16_t* __restrict__ state_b) {
  __shared__ float tile[32][33];
  int bid = blockIdx.x;
  int wid = threadIdx.x >> 6, lane = threadIdx.x & 63;

  if (bid < 4096) {
    // ---- build_idx ----
    int W = bid * 4 + wid;               // 0..16383
    int b = W >> 9, io = (W >> 8) & 1, n = W & 255;
    const float* p = edges + (size_t)(b * 256 + n) * 2048 + io * 1024;
    unsigned short* list = nbr + (size_t)W * 64;
    int base = 0;
    int ends[4];
#pragma unroll
    for (int e = 0; e < 4; ++e) {
#pragma unroll
      for (int ch = 0; ch < 4; ++ch) {
        int c = e * 256 + ch * 64 + lane;
        float v = p[c];
        unsigned long long mask = __ballot(v != 0.0f);
        int before = __popcll(mask & ((1ull << lane) - 1ull));
        if (v != 0.0f && (base + before) < 64) list[base + before] = (unsigned short)c;
        base += __popcll(mask);
      }
      ends[e] = base < 64 ? base : 64;
    }
    if (lane == 0)
      cnt4[W] = make_uchar4((unsigned char)ends[0], (unsigned char)ends[1],
                            (unsigned char)ends[2], (unsigned char)ends[3]);
  } else if (bid < 5120) {
    // ---- rowsum (W_in or W_out) ----
    const float* Wsrc = bid < 4608 ? W_in : W_out;
    float* wsum = bid < 4608 ? wsum_in : wsum_out;
    int row = (bid - (bid < 4608 ? 4096 : 4608)) * 4 + wid;   // < 2048
    const float4* p = reinterpret_cast<const float4*>(Wsrc + (size_t)row * 512);
    float s = 0.f;
#pragma unroll
    for (int i = 0; i < 2; ++i) {
      float4 v = p[lane + i * 64];
      s += v.x + v.y + v.z + v.w;
    }
#pragma unroll
    for (int off = 32; off > 0; off >>= 1) s += __shfl_down(s, off, 64);
    if (lane == 0) wsum[row] = s;
  } else if (bid < 7424) {
    // ---- Wall_t transpose: z=0 W_r, z=1 W_z, z=2 W_h (top 1024, zero-pad) --
    int r = bid - 5120;                   // 0..2303
    int bx = r & 15, by = (r >> 4) % 48, z = r / 768;
    const float* src = z == 0 ? W_r : z == 1 ? W_z : W_h;
    int Ksrc = z == 2 ? 1024 : 1536;
    bf16_t* d = Wall_t + (size_t)(z * 512) * 1536;
    int tx = threadIdx.x & 31, ty = threadIdx.x >> 5;
    int n0 = bx * 32, k0 = by * 32;
    if (k0 >= Ksrc) {
#pragma unroll
      for (int i = 0; i < 4; ++i)
        d[(size_t)(n0 + ty + i * 8) * 1536 + k0 + tx] = (bf16_t)0.0f;
      return;
    }
#pragma unroll
    for (int i = 0; i < 4; ++i)
      tile[ty + i * 8][tx] = src[(size_t)(k0 + ty + i * 8) * 512 + n0 + tx];
    __syncthreads();
#pragma unroll
    for (int i = 0; i < 4; ++i)
      d[(size_t)(n0 + ty + i * 8) * 1536 + k0 + tx] = (bf16_t)tile[tx][ty + i * 8];
  } else if (bid < 8192) {
    // ---- small transposes: z=0 Whb (W_h rows 1024:), z=1 Wbh, z=2 Wbc ----
    int r = bid - 7424;                   // 0..767
    int bx = r & 15, by = (r >> 4) & 15, z = r >> 8;
    const float* src = z == 0 ? (W_h + 1024 * 512) : z == 1 ? W_bh : W_bc;
    bf16_t* dst = z == 0 ? Whb_t : z == 1 ? Wbh_t : Wbc_t;
    int tx = threadIdx.x & 31, ty = threadIdx.x >> 5;
    int n0 = bx * 32, k0 = by * 32;
#pragma unroll
    for (int i = 0; i < 4; ++i)
      tile[ty + i * 8][tx] = src[(size_t)(k0 + ty + i * 8) * 512 + n0 + tx];
    __syncthreads();
#pragma unroll
    for (int i = 0; i < 4; ++i)
      dst[(size_t)(n0 + ty + i * 8) * 512 + k0 + tx] = (bf16_t)tile[tx][ty + i * 8];
  } else {
    // ---- state init ----
    int i = (bid - 8192) * 256 + threadIdx.x;   // < 1048576
    float4 v = reinterpret_cast<const float4*>(prop_state)[i];
    reinterpret_cast<float4*>(out_state)[i] = v;
    bf16x4_t o;
    o[0] = (bf16_t)v.x; o[1] = (bf16_t)v.y; o[2] = (bf16_t)v.z; o[3] = (bf16_t)v.w;
    *reinterpret_cast<bf16x4_t*>(state_b + (size_t)i * 4) = o;
  }
}

// ---------------- sparse aggregation ----------------
__global__ __launch_bounds__(256) void k_agg_sparse(const unsigned short* __restrict__ nbr,
                                                    const uchar4* __restrict__ cnt4,
                                                    const bf16_t* __restrict__ state_b,
                                                    const float* __restrict__ wsum_in,
                                                    const float* __restrict__ wsum_out,
                                                    const float* __restrict__ b_in,
                                                    const float* __restrict__ b_out,
                                                    bf16_t* __restrict__ ain_b,
                                                    bf16_t* __restrict__ aout_b) {
  int wid = threadIdx.x >> 6, lane = threadIdx.x & 63;
  int W = blockIdx.x * 4 + wid;          // 0..16383
  int b = W >> 9, io = (W >> 8) & 1, n = W & 255;
  const float* wsel = io ? wsum_out : wsum_in;
  const float* bsel = io ? b_out : b_in;
  int d0 = lane << 3;
  float w[4][8], bi[4][8];
#pragma unroll
  for (int e = 0; e < 4; ++e) {
#pragma unroll
    for (int t = 0; t < 8; t += 4) {
      float4 v = *reinterpret_cast<const float4*>(wsel + e * 512 + d0 + t);
      w[e][t] = v.x; w[e][t + 1] = v.y; w[e][t + 2] = v.z; w[e][t + 3] = v.w;
      float4 u = *reinterpret_cast<const float4*>(bsel + e * 512 + d0 + t);
      bi[e][t] = u.x; bi[e][t + 1] = u.y; bi[e][t + 2] = u.z; bi[e][t + 3] = u.w;
    }
  }
  int mycode = nbr[(size_t)W * 64 + lane];
  uchar4 ce = cnt4[W];
  float acc[8];
#pragma unroll
  for (int t = 0; t < 8; ++t) acc[t] = 0.f;
  const bf16_t* Sb = state_b + ((size_t)b << 17) + d0;
  int start = 0;
#pragma unroll
  for (int e = 0; e < 4; ++e) {
    int end = (e == 0) ? ce.x : (e == 1) ? ce.y : (e == 2) ? ce.z : ce.w;
    float fc = (float)(end - start);
#pragma unroll
    for (int t = 0; t < 8; ++t) acc[t] += fc * bi[e][t];
    for (int j = start; j < end; ++j) {
      int c = __shfl(mycode, j, 64);
      int m = c & 255;
      bf16x8 s = *reinterpret_cast<const bf16x8*>(Sb + ((size_t)m << 9));
#pragma unroll
      for (int t = 0; t < 8; ++t) acc[t] += (float)s[t] * w[e][t];
    }
    start = end;
  }
  bf16x8 o;
#pragma unroll
  for (int t = 0; t < 8; ++t) o[t] = (bf16_t)acc[t];
  bf16_t* dst = io ? aout_b : ain_b;
  *reinterpret_cast<bf16x8*>(dst + (size_t)(b * 256 + n) * 512 + d0) = o;
}

// ---------------- wide gate GEMM: 128x128, 8 waves, BK=32 (r13 optimum) ----
// grid (64, 12); nt 0-3: r -> rs_b ; 4-7: z -> zb_b ; 8-11: h (K=1024) -> hp_b.
// Wave tile 64x32: wr = wid>>2, wc = wid&3. 24 waves/CU.
__global__ __launch_bounds__(512, 6) void k_gates(const bf16_t* __restrict__ ain_b,
                                                  const bf16_t* __restrict__ aout_b,
                                                  const bf16_t* __restrict__ state_row_b,
                                                  const bf16_t* __restrict__ Wall_t,
                                                  const float* __restrict__ b_r,
                                                  const float* __restrict__ b_z,
                                                  const float* __restrict__ b_h,
                                                  bf16_t* __restrict__ rs_b,
                                                  bf16_t* __restrict__ zb_b,
                                                  bf16_t* __restrict__ hp_b) {
  __shared__ __align__(16) char smem[32768];   // 2 bufs x (A 8KB + B 8KB)
  float* tr = (float*)smem;                    // epilogue reuse [128][36] = 18KB
  int tid = threadIdx.x;
  int lane = tid & 63, wid = tid >> 6;         // 8 waves
  int wr = wid >> 2, wc = wid & 3;             // 2M x 4N
  int mt = blockIdx.x, nt = blockIdx.y;        // 64 x 12
  int gm0 = mt * 128, gn0 = nt * 128;
  int l15 = lane & 15, q = lane >> 4, koff = q << 3;
  int nkt = (nt < 8) ? 48 : 32;                // h-region: skip zero-padded K
  f32x4 acc[4][2];
#pragma unroll
  for (int i = 0; i < 4; ++i)
#pragma unroll
    for (int j = 0; j < 2; ++j) acc[i][j] = f32x4{0.f, 0.f, 0.f, 0.f};

  auto stageAB = [&](int buf, int kt) {        // 2 loads/thread (1 A + 1 B)
    int blk = kt >> 4, kk = (kt & 15) << 5;
    const bf16_t* gA = (blk == 0 ? ain_b : blk == 1 ? aout_b : state_row_b)
                       + (size_t)gm0 * 512 + kk;
    bf16_t* base = (bf16_t*)(smem + buf * 16384);
    stage_lds16_128_w8(gA, 512, base);                                   // A 8KB
    stage_lds16_128_w8(Wall_t + (size_t)gn0 * 1536 + (kt << 5), 1536,
                       base + 4096);                                     // B 8KB
  };

  stageAB(0, 0);
  stageAB(1, 1);                               // 4 loads in flight per thread
  for (int kt = 0; kt < nkt; ++kt) {
    if (kt + 1 < nkt)
      asm volatile("s_waitcnt vmcnt(2)" ::: "memory");   // tile kt's loads done
    else
      asm volatile("s_waitcnt vmcnt(0)" ::: "memory");
    SCHED0(); SBAR(); SCHED0();                // publish tile kt to all waves
    const bf16_t* As = (const bf16_t*)(smem + (kt & 1) * 16384);
    const bf16_t* Bs = As + 4096;
    bf16x8 af[4], bfr[2];
#pragma unroll
    for (int i = 0; i < 4; ++i) af[i] = frag(As, wr * 64 + i * 16 + l15, koff);
#pragma unroll
    for (int j = 0; j < 2; ++j) bfr[j] = frag(Bs, wc * 32 + j * 16 + l15, koff);
#pragma unroll
    for (int i = 0; i < 4; ++i)
#pragma unroll
      for (int j = 0; j < 2; ++j)
        acc[i][j] = __builtin_amdgcn_mfma_f32_16x16x32_bf16(af[i], bfr[j], acc[i][j], 0, 0, 0);
    SCHED0(); SBAR(); SCHED0();                // all waves done reading this buf
    if (kt + 2 < nkt) stageAB(kt & 1, kt + 2); // refill; waited at iter kt+2
  }

  // coalesced epilogue: 4 passes of 128x32 via padded LDS transpose
  int region = nt >> 2;                        // 0:r 1:z 2:h
  int cn0 = gn0 - region * 512;                // local col base in [0,512)
  const float* bias = region == 0 ? b_r : region == 1 ? b_z : b_h;
#pragma unroll
  for (int p = 0; p < 4; ++p) {
    __syncthreads();
    if (wc == p) {                             // 2 waves (wr=0,1) cover 128 rows
#pragma unroll
      for (int i = 0; i < 4; ++i)
#pragma unroll
        for (int j = 0; j < 2; ++j)
#pragma unroll
          for (int rr = 0; rr < 4; ++rr)
            tr[(wr * 64 + i * 16 + q * 4 + rr) * 36 + j * 16 + l15] = acc[i][j][rr];
    }
    __syncthreads();
#pragma unroll
    for (int s = 0; s < 8; ++s) {
      int e = tid + (s << 9);                  // 0..4095
      int row = e >> 5, c = e & 31;
      int col = cn0 + (p << 5) + c;
      size_t idx = (size_t)(gm0 + row) * 512 + col;
      float x = tr[row * 36 + c] + bias[col];
      if (region == 0) {
        float rg = 1.0f / (1.0f + __expf(-x));
        rs_b[idx] = (bf16_t)(rg * (float)state_row_b[idx]);
      } else if (region == 1) {
        zb_b[idx] = (bf16_t)(1.0f / (1.0f + __expf(-x)));
      } else {
        hp_b[idx] = (bf16_t)x;
      }
    }
  }
}

// ---------------- small GEMM + GRU update: 64x128, 4 waves (r13) -----------
__global__ __launch_bounds__(256, 4) void k_gru(const bf16_t* __restrict__ rs_b,
                                                const bf16_t* __restrict__ Whb_t,
                                                const bf16_t* __restrict__ hp_b,
                                                const bf16_t* __restrict__ zb_b,
                                                float* __restrict__ state_f32,
                                                bf16_t* __restrict__ state_row_b) {
  __shared__ __align__(16) char smem[24576];   // 2 bufs x (A 4KB + B 8KB)
  float* tr = (float*)smem;                    // epilogue reuse (9KB)
  int mt = blockIdx.x, nt = blockIdx.y;        // 128 x 4
  int gm0 = mt * 64, gn0 = nt * 128;
  int lane = threadIdx.x & 63, wid = threadIdx.x >> 6;
  int wr = wid >> 1, wc = wid & 1;
  int l15 = lane & 15, q = lane >> 4, koff = q << 3;
  f32x4 acc[2][4];
#pragma unroll
  for (int i = 0; i < 2; ++i)
#pragma unroll
    for (int j = 0; j < 4; ++j) acc[i][j] = f32x4{0.f, 0.f, 0.f, 0.f};

  auto stageAB = [&](int buf, int kt) {        // 3 loads/thread
    bf16_t* base = (bf16_t*)(smem + buf * 12288);
    stage_lds16_64(rs_b + (size_t)gm0 * 512 + (kt << 5), 512, base);
    stage_lds16(Whb_t + (size_t)gn0 * 512 + (kt << 5), 512, base + 2048);
  };

  stageAB(0, 0);
  stageAB(1, 1);                               // 6 loads in flight
  for (int kt = 0; kt < 16; ++kt) {
    if (kt + 1 < 16)
      asm volatile("s_waitcnt vmcnt(3)" ::: "memory");
    else
      asm volatile("s_waitcnt vmcnt(0)" ::: "memory");
    SCHED0(); SBAR(); SCHED0();
    const bf16_t* As = (const bf16_t*)(smem + (kt & 1) * 12288);
    const bf16_t* Bs = As + 2048;
    bf16x8 af[2], bfr[4];
#pragma unroll
    for (int i = 0; i < 2; ++i) af[i] = frag(As, wr * 32 + i * 16 + l15, koff);
#pragma unroll
    for (int j = 0; j < 4; ++j) bfr[j] = frag(Bs, wc * 64 + j * 16 + l15, koff);
#pragma unroll
    for (int i = 0; i < 2; ++i)
#pragma unroll
      for (int j = 0; j < 4; ++j)
        acc[i][j] = __builtin_amdgcn_mfma_f32_16x16x32_bf16(af[i], bfr[j], acc[i][j], 0, 0, 0);
    SCHED0(); SBAR(); SCHED0();
    if (kt + 2 < 16) stageAB(kt & 1, kt + 2);
  }

  // coalesced epilogue: 4 passes of 64x32
#pragma unroll
  for (int p = 0; p < 4; ++p) {
    __syncthreads();
    if (wc == (p >> 1)) {
      int j0 = (p & 1) << 1;
#pragma unroll
      for (int jj = 0; jj < 2; ++jj) {
        int j = j0 + jj;
        int c = j * 16 + l15 - ((p & 1) << 5);
#pragma unroll
        for (int i = 0; i < 2; ++i)
#pragma unroll
          for (int rr = 0; rr < 4; ++rr) {
            int row = wr * 32 + i * 16 + q * 4 + rr;
            tr[row * 36 + c] = acc[i][j][rr];
          }
      }
    }
    __syncthreads();
#pragma unroll
    for (int s = 0; s < 8; ++s) {
      int e = threadIdx.x + (s << 8);                 // 0..2047
      int row = e >> 5, c = e & 31;
      int col = gn0 + (p << 5) + c;
      size_t idx = (size_t)(gm0 + row) * 512 + col;
      float x = tr[row * 36 + c] + (float)hp_b[idx];
      float hh = x > 0.0f ? x : 0.01f * x;
      float z = (float)zb_b[idx];
      float so = state_f32[idx];
      float sn = (1.0f - z) * so + z * hh;
      state_f32[idx] = sn;
      state_row_b[idx] = (bf16_t)sn;
    }
  }
}

// ---------------- bridge ----------------

__global__ __launch_bounds__(256) void k_join(const float* __restrict__ state_f32,
                                              bf16_t* __restrict__ join_b) {
  int idx = blockIdx.x * 256 + threadIdx.x;
  float s = 0.f;
#pragma unroll
  for (int b = 0; b < 32; ++b) s += state_f32[(size_t)b * 131072 + idx];
  join_b[idx] = (bf16_t)(s * (1.0f / 32.0f));
}

__global__ __launch_bounds__(256) void k_bridge(const bf16_t* __restrict__ join_b,
                                                const bf16_t* __restrict__ Wbh_t,
                                                const bf16_t* __restrict__ Wbc_t,
                                                const float* __restrict__ b_bh,
                                                const float* __restrict__ b_bc,
                                                float* __restrict__ out_h,
                                                float* __restrict__ out_c) {
  __shared__ bf16_t As[2][4096];
  __shared__ bf16_t Bs[2][4096];
  int mt = blockIdx.x, nt = blockIdx.y, hc = blockIdx.z;
  const bf16_t* Wt = hc ? Wbc_t : Wbh_t;
  const float* bias = hc ? b_bc : b_bh;
  float* dst = hc ? out_c : out_h;
  int gm0 = mt * 128, gn0 = nt * 128;
  int lane = threadIdx.x & 63, wid = threadIdx.x >> 6;
  int wr = wid >> 1, wc = wid & 1;
  int l15 = lane & 15, koff = (lane >> 4) << 3;
  f32x4 acc[4][4];
#pragma unroll
  for (int i = 0; i < 4; ++i)
#pragma unroll
    for (int j = 0; j < 4; ++j) acc[i][j] = f32x4{0.f, 0.f, 0.f, 0.f};
  auto stageAB = [&](int buf, int kt) {
    stage_lds16(join_b + (size_t)gm0 * 512 + (kt << 5), 512, As[buf]);
    stage_lds16(Wt + (size_t)gn0 * 512 + (kt << 5), 512, Bs[buf]);
  };
  stageAB(0, 0);
  __syncthreads();
  int cur = 0;
  for (int kt = 0; kt < 16; ++kt) {
    if (kt + 1 < 16) stageAB(cur ^ 1, kt + 1);
    bf16x8 af[4], bfr[4];
#pragma unroll
    for (int i = 0; i < 4; ++i) af[i] = frag(As[cur], wr * 64 + i * 16 + l15, koff);
#pragma unroll
    for (int j = 0; j < 4; ++j) bfr[j] = frag(Bs[cur], wc * 64 + j * 16 + l15, koff);
#pragma unroll
    for (int i = 0; i < 4; ++i)
#pragma unroll
      for (int j = 0; j < 4; ++j)
        acc[i][j] = __builtin_amdgcn_mfma_f32_16x16x32_bf16(af[i], bfr[j], acc[i][j], 0, 0, 0);
    __syncthreads();
    cur ^= 1;
  }
  int lr0 = (lane >> 4) << 2;
#pragma unroll
  for (int j = 0; j < 4; ++j) {
    int col = gn0 + wc * 64 + j * 16 + l15;
    float bv = bias[col];
#pragma unroll
    for (int i = 0; i < 4; ++i) {
#pragma unroll
      for (int r = 0; r < 4; ++r) {
        int row = gm0 + wr * 64 + i * 16 + lr0 + r;
        float v = acc[i][j][r] + bv;
        v = v > 0.f ? v : 0.f;
#pragma unroll
        for (int rep = 0; rep < 4; ++rep)
          dst[(size_t)rep * 131072 + (size_t)row * 512 + col] = v;
      }
    }
  }
}

// ---------------- launch ----------------

extern "C" void kernel_launch(void* const* d_in, const int* in_sizes, int n_in,
                              void* d_out, int out_size, void* d_ws, size_t ws_size,
                              hipStream_t stream) {
  const float* prop_state = (const float*)d_in[0];
  const float* edges = (const float*)d_in[1];
  const float* W_in = (const float*)d_in[2];
  const float* b_in = (const float*)d_in[3];
  const float* W_out = (const float*)d_in[4];
  const float* b_out = (const float*)d_in[5];
  const float* W_r = (const float*)d_in[6];
  const float* b_r = (const float*)d_in[7];
  const float* W_z = (const float*)d_in[8];
  const float* b_z = (const float*)d_in[9];
  const float* W_h = (const float*)d_in[10];
  const float* b_h = (const float*)d_in[11];
  const float* W_bh = (const float*)d_in[12];
  const float* b_bh = (const float*)d_in[13];
  const float* W_bc = (const float*)d_in[14];
  const float* b_bc = (const float*)d_in[15];

  float* out_state = (float*)d_out;          // 32*256*512 f32
  float* out_h = out_state + 4194304;        // 4*256*512
  float* out_c = out_h + 524288;

  char* ws = (char*)d_ws;
  size_t off = 0;
  auto alloc = [&](size_t bytes) -> void* {
    void* p = ws + off;
    off += (bytes + 255) & ~(size_t)255;
    return p;
  };
  unsigned short* nbr = (unsigned short*)alloc(16384ull * 64 * 2);
  uchar4* cnt4   = (uchar4*)alloc(16384ull * 4);
  float* wsum_in  = (float*)alloc(2048ull * 4);
  float* wsum_out = (float*)alloc(2048ull * 4);
  bf16_t* Wall_t = (bf16_t*)alloc(1536ull * 1536 * 2); // [n=1536][k=1536]
  bf16_t* Whb_t  = (bf16_t*)alloc(512ull * 512 * 2);   // W_h rows 1024:1536
  bf16_t* Wbh_t  = (bf16_t*)alloc(512ull * 512 * 2);
  bf16_t* Wbc_t  = (bf16_t*)alloc(512ull * 512 * 2);
  bf16_t* state_b = (bf16_t*)alloc(4194304ull * 2);    // row-major bf16 state
  bf16_t* ain_b  = (bf16_t*)alloc(4194304ull * 2);
  bf16_t* aout_b = (bf16_t*)alloc(4194304ull * 2);
  bf16_t* rs_b   = (bf16_t*)alloc(4194304ull * 2);
  bf16_t* zb_b   = (bf16_t*)alloc(4194304ull * 2);
  bf16_t* hp_b   = (bf16_t*)alloc(4194304ull * 2);
  bf16_t* join_b = (bf16_t*)alloc(131072ull * 2);
  if (off > ws_size) return;  // insufficient workspace -> output stays poisoned

  // fused prep: one launch, all independent prep tasks overlapped
  k_prep_all<<<12288, 256, 0, stream>>>(edges, nbr, cnt4,
                                        W_in, W_out, wsum_in, wsum_out,
                                        W_r, W_z, W_h, Wall_t,
                                        W_bh, W_bc, Whb_t, Wbh_t, Wbc_t,
                                        prop_state, out_state, state_b);

  // 4 propagation steps
  for (int step = 0; step < 4; ++step) {
    k_agg_sparse<<<4096, 256, 0, stream>>>(nbr, cnt4, state_b, wsum_in, wsum_out,
                                           b_in, b_out, ain_b, aout_b);
    k_gates<<<dim3(64, 12), 512, 0, stream>>>(ain_b, aout_b, state_b, Wall_t,
                                              b_r, b_z, b_h, rs_b, zb_b, hp_b);
    k_gru<<<dim3(128, 4), 256, 0, stream>>>(rs_b, Whb_t, hp_b, zb_b,
                                            out_state, state_b);
  }

  // bridge
  k_join<<<512, 256, 0, stream>>>(out_state, join_b);
  k_bridge<<<dim3(2, 4, 2), 256, 0, stream>>>(join_b, Wbh_t, Wbc_t, b_bh, b_bc, out_h, out_c);
}